// Round 3
// baseline (5818.892 us; speedup 1.0000x reference)
//
#include <hip/hip_runtime.h>

typedef __attribute__((ext_vector_type(8))) short bf16x8;
typedef __attribute__((ext_vector_type(4))) float f32x4;

static __device__ __forceinline__ unsigned short f2bf(float f) {
    unsigned int u = __float_as_uint(f);
    u += 0x7fffu + ((u >> 16) & 1u);   // round-to-nearest-even
    return (unsigned short)(u >> 16);
}
static __device__ __forceinline__ float bf2f(unsigned short h) {
    return __uint_as_float(((unsigned int)h) << 16);
}

#define BSH 6
#define BUCKET 64
#define NBMAX 1600

// ---------------- misc ----------------

__global__ void zero_k(int* p, int n) {
    int i = blockIdx.x * 256 + threadIdx.x;
    if (i < n) p[i] = 0;
}

struct PrepArgs {
    const float* W[10];
    const float* Wa[10];
    const float* b1a; const float* b1b; const float* b2a; const float* b2b;
};

// blocks 0..639: transpose+bf16 (slot = blk>>6); block 640: combined biases
__global__ void prep_k(PrepArgs pa, unsigned short* __restrict__ Wt,
                       float* __restrict__ bc1, float* __restrict__ bc2) {
    int blk = blockIdx.x;
    if (blk < 640) {
        int slot = blk >> 6;
        int i = ((blk & 63) << 8) + threadIdx.x;   // 0..16383
        int k = i >> 7, n = i & 127;
        float v = pa.W[slot][i];
        const float* w2 = pa.Wa[slot];
        if (w2) v += w2[i];
        Wt[slot * 16384 + n * 128 + k] = f2bf(v);
    } else {
        int t = threadIdx.x;
        if (t < 128) bc1[t] = pa.b1a[t] + pa.b1b[t];
        else bc2[t - 128] = pa.b2a[t - 128] + pa.b2b[t - 128];
    }
}

__global__ void f2bf_vec_k(const float* __restrict__ x, unsigned short* __restrict__ y, int n4) {
    int i = blockIdx.x * 256 + threadIdx.x;
    if (i < n4) {
        float4 v = ((const float4*)x)[i];
        ushort4 o;
        o.x = f2bf(v.x); o.y = f2bf(v.y); o.z = f2bf(v.z); o.w = f2bf(v.w);
        ((ushort4*)y)[i] = o;
    }
}

// ---------------- bucket build ----------------

__global__ void bhist_k(const int* __restrict__ dst, int E, int* __restrict__ bcnt, int nb) {
    __shared__ int h[NBMAX];
    for (int i = threadIdx.x; i < nb; i += 256) h[i] = 0;
    __syncthreads();
    for (int e = blockIdx.x * 256 + threadIdx.x; e < E; e += gridDim.x * 256)
        atomicAdd(&h[dst[e] >> BSH], 1);
    __syncthreads();
    for (int i = threadIdx.x; i < nb; i += 256)
        if (h[i]) atomicAdd(&bcnt[i], h[i]);
}

// single block, 1024 threads; exclusive scan of bcnt[0..nb) -> boff[0..nb]; zero bcur
__global__ void bscan_k(const int* __restrict__ bcnt, int nb, int* __restrict__ boff,
                        int* __restrict__ bcur) {
    __shared__ int s[1024];
    int t = threadIdx.x;
    int e0 = 2 * t, e1 = 2 * t + 1;
    int v0 = (e0 < nb) ? bcnt[e0] : 0;
    int v1 = (e1 < nb) ? bcnt[e1] : 0;
    s[t] = v0 + v1;
    __syncthreads();
    for (int o = 1; o < 1024; o <<= 1) {
        int x = (t >= o) ? s[t - o] : 0;
        __syncthreads();
        s[t] += x;
        __syncthreads();
    }
    int P = s[t] - (v0 + v1);            // exclusive prefix at element e0
    if (e0 <= nb) { boff[e0] = P; if (e0 < nb) bcur[e0] = 0; }
    if (e1 <= nb) { boff[e1] = P + v0; if (e1 < nb) bcur[e1] = 0; }
}

// each block: 8192-edge chunk; privatized bucket scatter of packed pairs
__global__ __launch_bounds__(256) void bscatter_k(const int* __restrict__ src,
                                                  const int* __restrict__ dst, int E,
                                                  const int* __restrict__ boff,
                                                  int* __restrict__ bcur,
                                                  unsigned* __restrict__ pairs, int nb) {
    __shared__ int h[NBMAX];
    __shared__ int base[NBMAX];
    int t = threadIdx.x;
    for (int i = t; i < nb; i += 256) h[i] = 0;
    __syncthreads();
    int e0 = blockIdx.x * 8192;
    for (int i = 0; i < 32; i++) {
        int e = e0 + i * 256 + t;
        if (e < E) atomicAdd(&h[dst[e] >> BSH], 1);
    }
    __syncthreads();
    for (int i = t; i < nb; i += 256) {
        int c = h[i];
        base[i] = c ? (boff[i] + atomicAdd(&bcur[i], c)) : 0;
    }
    __syncthreads();
    for (int i = t; i < nb; i += 256) h[i] = 0;
    __syncthreads();
    for (int i = 0; i < 32; i++) {
        int e = e0 + i * 256 + t;
        if (e < E) {
            int d = dst[e];
            int b = d >> BSH;
            int pos = base[b] + atomicAdd(&h[b], 1);
            pairs[pos] = ((unsigned)(d & (BUCKET - 1)) << 17) | (unsigned)src[e];
        }
    }
}

// ---------------- MFMA GEMMs ----------------
// A-frag: lane l holds A[row0 + (l&15)][kc*32 + (l>>4)*8 + 0..7]
// C/D: lane l, reg j -> row (l>>4)*4 + j, col l&15   [m89]

__global__ __launch_bounds__(256) void gemm_single_k(const unsigned short* __restrict__ A, int N,
                                                     const unsigned short* __restrict__ Wt,
                                                     unsigned short* __restrict__ Cb) {
    int wv = threadIdx.x >> 6, lane = threadIdx.x & 63;
    int r16 = lane & 15, g = lane >> 4;
    int row0 = blockIdx.x * 64 + wv * 16;
    int arow = row0 + r16;
    int arow_c = arow < N ? arow : N - 1;
    const bf16x8* Arow = (const bf16x8*)(A + (size_t)arow_c * 128);
    bf16x8 af[4];
#pragma unroll
    for (int kc = 0; kc < 4; kc++) af[kc] = Arow[kc * 4 + g];
    f32x4 acc[8];
#pragma unroll
    for (int ct = 0; ct < 8; ct++) { f32x4 z = {0.f, 0.f, 0.f, 0.f}; acc[ct] = z; }
#pragma unroll
    for (int kc = 0; kc < 4; kc++) {
#pragma unroll
        for (int ct = 0; ct < 8; ct++) {
            bf16x8 bfrag = *(const bf16x8*)(Wt + ((ct * 16 + r16) << 7) + kc * 32 + g * 8);
            acc[ct] = __builtin_amdgcn_mfma_f32_16x16x32_bf16(af[kc], bfrag, acc[ct], 0, 0, 0);
        }
    }
#pragma unroll
    for (int ct = 0; ct < 8; ct++) {
        int col = ct * 16 + r16;
#pragma unroll
        for (int j = 0; j < 4; j++) {
            int r = row0 + g * 4 + j;
            if (r < N) Cb[(size_t)r * 128 + col] = f2bf(acc[ct][j]);
        }
    }
}

// C1 = A@W1 + bias1 (f32), C2 = A@W2 (bf16); shared A-fragments
__global__ __launch_bounds__(256) void gemm_dual_k(const unsigned short* __restrict__ A, int N,
                                                   const unsigned short* __restrict__ Wt1,
                                                   const float* __restrict__ bias1,
                                                   float* __restrict__ C1,
                                                   const unsigned short* __restrict__ Wt2,
                                                   unsigned short* __restrict__ C2) {
    int wv = threadIdx.x >> 6, lane = threadIdx.x & 63;
    int r16 = lane & 15, g = lane >> 4;
    int row0 = blockIdx.x * 64 + wv * 16;
    int arow = row0 + r16;
    int arow_c = arow < N ? arow : N - 1;
    const bf16x8* Arow = (const bf16x8*)(A + (size_t)arow_c * 128);
    bf16x8 af[4];
#pragma unroll
    for (int kc = 0; kc < 4; kc++) af[kc] = Arow[kc * 4 + g];
    f32x4 acc1[8], acc2[8];
#pragma unroll
    for (int ct = 0; ct < 8; ct++) {
        f32x4 z = {0.f, 0.f, 0.f, 0.f};
        acc1[ct] = z; acc2[ct] = z;
    }
#pragma unroll
    for (int kc = 0; kc < 4; kc++) {
#pragma unroll
        for (int ct = 0; ct < 8; ct++) {
            int wo = ((ct * 16 + r16) << 7) + kc * 32 + g * 8;
            bf16x8 b1 = *(const bf16x8*)(Wt1 + wo);
            acc1[ct] = __builtin_amdgcn_mfma_f32_16x16x32_bf16(af[kc], b1, acc1[ct], 0, 0, 0);
            bf16x8 b2 = *(const bf16x8*)(Wt2 + wo);
            acc2[ct] = __builtin_amdgcn_mfma_f32_16x16x32_bf16(af[kc], b2, acc2[ct], 0, 0, 0);
        }
    }
#pragma unroll
    for (int ct = 0; ct < 8; ct++) {
        int col = ct * 16 + r16;
        float b = bias1[col];
#pragma unroll
        for (int j = 0; j < 4; j++) {
            int r = row0 + g * 4 + j;
            if (r < N) {
                C1[(size_t)r * 128 + col] = acc1[ct][j] + b;
                C2[(size_t)r * 128 + col] = f2bf(acc2[ct][j]);
            }
        }
    }
}

// ---------------- fused aggregation ----------------
// One block per 64-dst bucket. LDS acc (swizzled: element e at pos (e&3)*32+(e>>2)),
// init from Z, accumulate scaled gathered Y rows of up to 2 relations, finalize.
template <int NREL, int RELU, int OUTBF16>
__global__ __launch_bounds__(512) void fusedagg_k(const float* __restrict__ Zin, int Ndst,
                                                  const unsigned* __restrict__ pairs0,
                                                  const int* __restrict__ boff0,
                                                  const unsigned short* __restrict__ Y0,
                                                  const unsigned* __restrict__ pairs1,
                                                  const int* __restrict__ boff1,
                                                  const unsigned short* __restrict__ Y1,
                                                  float* __restrict__ OutF,
                                                  unsigned short* __restrict__ OutB) {
    __shared__ float acc[BUCKET * 128];
    __shared__ float inv[2][BUCKET];
    __shared__ int cnt[2][BUCKET];
    int t = threadIdx.x;
    int b = blockIdx.x;
    int dst0 = b << BSH;
    int nrow = Ndst - dst0; if (nrow > BUCKET) nrow = BUCKET;

    if (t < BUCKET) { cnt[0][t] = 0; cnt[1][t] = 0; }
    __syncthreads();

    int j00 = boff0[b], j01 = boff0[b + 1];
    for (int j = j00 + t; j < j01; j += 512) atomicAdd(&cnt[0][(pairs0[j] >> 17) & (BUCKET - 1)], 1);
    int j10 = 0, j11 = 0;
    if (NREL == 2) {
        j10 = boff1[b]; j11 = boff1[b + 1];
        for (int j = j10 + t; j < j11; j += 512) atomicAdd(&cnt[1][(pairs1[j] >> 17) & (BUCKET - 1)], 1);
    }
    // init acc from Z (swizzled store)
    for (int c = t; c < BUCKET * 32; c += 512) {
        int r = c >> 5, m = c & 31;
        float4 z = make_float4(0.f, 0.f, 0.f, 0.f);
        if (r < nrow) z = ((const float4*)Zin)[(size_t)(dst0 + r) * 32 + m];
        acc[r * 128 + m] = z.x;
        acc[r * 128 + 32 + m] = z.y;
        acc[r * 128 + 64 + m] = z.z;
        acc[r * 128 + 96 + m] = z.w;
    }
    __syncthreads();
    if (t < BUCKET) {
        int c = cnt[0][t];
        inv[0][t] = 1.f / (float)(c > 0 ? c : 1);
        c = cnt[1][t];
        inv[1][t] = 1.f / (float)(c > 0 ? c : 1);
    }
    __syncthreads();

    int hw = t >> 5, q = t & 31;   // 16 half-waves, 32 lanes each
#pragma unroll 1
    for (int rel = 0; rel < NREL; rel++) {
        const unsigned* pairs = rel ? pairs1 : pairs0;
        const unsigned short* Y = rel ? Y1 : Y0;
        int ja = rel ? j10 : j00, jb = rel ? j11 : j01;
        for (int j = ja + hw; j < jb; j += 32) {
            unsigned p1 = pairs[j];
            int j2 = j + 16;
            bool has2 = j2 < jb;
            unsigned p2 = has2 ? pairs[j2] : p1;
            int s1 = p1 & 0x1ffff, d1 = (p1 >> 17) & (BUCKET - 1);
            int s2 = p2 & 0x1ffff, d2 = (p2 >> 17) & (BUCKET - 1);
            ushort4 v1 = *(const ushort4*)(Y + ((size_t)s1 << 7) + (q << 2));
            ushort4 v2 = *(const ushort4*)(Y + ((size_t)s2 << 7) + (q << 2));
            float sc1 = inv[rel][d1];
            float sc2 = has2 ? inv[rel][d2] : 0.f;
            atomicAdd(&acc[d1 * 128 + q], bf2f(v1.x) * sc1);
            atomicAdd(&acc[d1 * 128 + 32 + q], bf2f(v1.y) * sc1);
            atomicAdd(&acc[d1 * 128 + 64 + q], bf2f(v1.z) * sc1);
            atomicAdd(&acc[d1 * 128 + 96 + q], bf2f(v1.w) * sc1);
            atomicAdd(&acc[d2 * 128 + q], bf2f(v2.x) * sc2);
            atomicAdd(&acc[d2 * 128 + 32 + q], bf2f(v2.y) * sc2);
            atomicAdd(&acc[d2 * 128 + 64 + q], bf2f(v2.z) * sc2);
            atomicAdd(&acc[d2 * 128 + 96 + q], bf2f(v2.w) * sc2);
        }
    }
    __syncthreads();
    // finalize
    for (int c = t; c < BUCKET * 32; c += 512) {
        int r = c >> 5, m = c & 31;
        if (r < nrow) {
            float x0 = acc[r * 128 + m];
            float x1 = acc[r * 128 + 32 + m];
            float x2 = acc[r * 128 + 64 + m];
            float x3 = acc[r * 128 + 96 + m];
            if (RELU) {
                x0 = fmaxf(x0, 0.f); x1 = fmaxf(x1, 0.f);
                x2 = fmaxf(x2, 0.f); x3 = fmaxf(x3, 0.f);
            }
            size_t o = (size_t)(dst0 + r) * 128 + (m << 2);
            if (OUTBF16) {
                ushort4 ov;
                ov.x = f2bf(x0); ov.y = f2bf(x1); ov.z = f2bf(x2); ov.w = f2bf(x3);
                *(ushort4*)(OutB + o) = ov;
            } else {
                *(float4*)(OutF + o) = make_float4(x0, x1, x2, x3);
            }
        }
    }
}

// ---------------- launch ----------------

static inline size_t align256(size_t x) { return (x + 255) & ~size_t(255); }

extern "C" void kernel_launch(void* const* d_in, const int* in_sizes, int n_in,
                              void* d_out, int out_size, void* d_ws, size_t ws_size,
                              hipStream_t stream) {
    const float* x_kw = (const float*)d_in[0];
    const float* x_rt = (const float*)d_in[1];
    const int* src_a = (const int*)d_in[2];
    const int* dst_a = (const int*)d_in[3];
    const int* src_b = (const int*)d_in[4];
    const int* dst_b = (const int*)d_in[5];
    const int* src_c = (const int*)d_in[6];
    const int* dst_c = (const int*)d_in[7];
    const float *Wl1a = (const float*)d_in[8],  *bl1a = (const float*)d_in[9],  *Wr1a = (const float*)d_in[10];
    const float *Wl1b = (const float*)d_in[11], *bl1b = (const float*)d_in[12], *Wr1b = (const float*)d_in[13];
    const float *Wl1c = (const float*)d_in[14], *bl1c = (const float*)d_in[15], *Wr1c = (const float*)d_in[16];
    const float *Wl2a = (const float*)d_in[17], *bl2a = (const float*)d_in[18], *Wr2a = (const float*)d_in[19];
    const float *Wl2b = (const float*)d_in[20], *bl2b = (const float*)d_in[21], *Wr2b = (const float*)d_in[22];
    const float *Wl2c = (const float*)d_in[23], *bl2c = (const float*)d_in[24], *Wr2c = (const float*)d_in[25];

    const int NKW = in_sizes[0] / 128;
    const int NRT = in_sizes[1] / 128;
    const int EA = in_sizes[2], EB = in_sizes[4], EC = in_sizes[6];
    const int nb_kw = (NKW + BUCKET - 1) / BUCKET;
    const int nb_rt = (NRT + BUCKET - 1) / BUCKET;

    char* ws = (char*)d_ws;
    size_t off = 0;
    auto alloc = [&](size_t bytes) -> char* {
        off = align256(off);
        char* p = ws + off;
        off += bytes;
        return p;
    };
    unsigned short* Wt = (unsigned short*)alloc(10 * 16384 * 2);
    float* bc1 = (float*)alloc(128 * 4);
    float* bc2 = (float*)alloc(128 * 4);
    int* bcnt_a = (int*)alloc(NBMAX * 4);
    int* bcnt_b = (int*)alloc(NBMAX * 4);
    int* bcnt_c = (int*)alloc(NBMAX * 4);
    int* boff_a = (int*)alloc((NBMAX + 1) * 4);
    int* boff_b = (int*)alloc((NBMAX + 1) * 4);
    int* boff_c = (int*)alloc((NBMAX + 1) * 4);
    int* bcur_a = (int*)alloc(NBMAX * 4);
    int* bcur_b = (int*)alloc(NBMAX * 4);
    int* bcur_c = (int*)alloc(NBMAX * 4);
    unsigned* pairs_a = (unsigned*)alloc((size_t)EA * 4);
    unsigned* pairs_b = (unsigned*)alloc((size_t)EB * 4);
    unsigned* pairs_c = (unsigned*)alloc((size_t)EC * 4);
    unsigned short* xkw_bf = (unsigned short*)alloc((size_t)NKW * 128 * 2);
    unsigned short* xrt_bf = (unsigned short*)alloc((size_t)NRT * 128 * 2);
    unsigned short* Ya = (unsigned short*)alloc((size_t)NRT * 128 * 2);
    unsigned short* Yb = (unsigned short*)alloc((size_t)NKW * 128 * 2);
    unsigned short* Yc = (unsigned short*)alloc((size_t)NRT * 128 * 2);
    (void)ws_size;
    unsigned short* kw1_bf = xkw_bf;   // alias: x_kw bf16 dead after L1 GEMMs
    unsigned short* rt1_bf = xrt_bf;

    float* out_kw = (float*)d_out;
    float* out_rt = out_kw + (size_t)NKW * 128;

    // ---- prep: weights (transposed bf16) + combined biases ----
    PrepArgs pa;
    pa.W[0] = Wr1a; pa.Wa[0] = Wr1b;   // W0 = (Wr1a+Wr1b)^T
    pa.W[1] = Wl1a; pa.Wa[1] = nullptr;
    pa.W[2] = Wl1b; pa.Wa[2] = nullptr;
    pa.W[3] = Wl1c; pa.Wa[3] = nullptr;
    pa.W[4] = Wr1c; pa.Wa[4] = nullptr;
    pa.W[5] = Wr2a; pa.Wa[5] = Wr2b;
    pa.W[6] = Wl2a; pa.Wa[6] = nullptr;
    pa.W[7] = Wl2b; pa.Wa[7] = nullptr;
    pa.W[8] = Wl2c; pa.Wa[8] = nullptr;
    pa.W[9] = Wr2c; pa.Wa[9] = nullptr;
    pa.b1a = bl1a; pa.b1b = bl1b; pa.b2a = bl2a; pa.b2b = bl2b;
    prep_k<<<641, 256, 0, stream>>>(pa, Wt, bc1, bc2);
    unsigned short* W0 = Wt + 0 * 16384;
    unsigned short* W1 = Wt + 1 * 16384;
    unsigned short* W2 = Wt + 2 * 16384;
    unsigned short* W3 = Wt + 3 * 16384;
    unsigned short* W4 = Wt + 4 * 16384;
    unsigned short* W5 = Wt + 5 * 16384;
    unsigned short* W6 = Wt + 6 * 16384;
    unsigned short* W7 = Wt + 7 * 16384;
    unsigned short* W8 = Wt + 8 * 16384;
    unsigned short* W9 = Wt + 9 * 16384;

    f2bf_vec_k<<<(NKW * 32 + 255) / 256, 256, 0, stream>>>(x_kw, xkw_bf, NKW * 32);
    f2bf_vec_k<<<(NRT * 32 + 255) / 256, 256, 0, stream>>>(x_rt, xrt_bf, NRT * 32);

    // ---- bucket build per relation ----
    auto build = [&](const int* src, const int* dst, int E, int nb, int* bcnt, int* boff,
                     int* bcur, unsigned* pairs) {
        zero_k<<<(nb + 255) / 256, 256, 0, stream>>>(bcnt, nb);
        bhist_k<<<256, 256, 0, stream>>>(dst, E, bcnt, nb);
        bscan_k<<<1, 1024, 0, stream>>>(bcnt, nb, boff, bcur);
        bscatter_k<<<(E + 8191) / 8192, 256, 0, stream>>>(src, dst, E, boff, bcur, pairs, nb);
    };
    build(src_a, dst_a, EA, nb_kw, bcnt_a, boff_a, bcur_a, pairs_a);
    build(src_b, dst_b, EB, nb_kw, bcnt_b, boff_b, bcur_b, pairs_b);
    build(src_c, dst_c, EC, nb_rt, bcnt_c, boff_c, bcur_c, pairs_c);

    // ---- layer 1 ----
    gemm_dual_k<<<(NKW + 63) / 64, 256, 0, stream>>>(xkw_bf, NKW, W0, bc1, out_kw, W2, Yb);
    gemm_dual_k<<<(NRT + 63) / 64, 256, 0, stream>>>(xrt_bf, NRT, W4, bl1c, out_rt, W1, Ya);
    gemm_single_k<<<(NRT + 63) / 64, 256, 0, stream>>>(xrt_bf, NRT, W3, Yc);
    fusedagg_k<2, 1, 1><<<nb_kw, 512, 0, stream>>>(out_kw, NKW, pairs_a, boff_a, Ya,
                                                   pairs_b, boff_b, Yb, nullptr, kw1_bf);
    fusedagg_k<1, 1, 1><<<nb_rt, 512, 0, stream>>>(out_rt, NRT, pairs_c, boff_c, Yc,
                                                   nullptr, nullptr, nullptr, nullptr, rt1_bf);

    // ---- layer 2 ----
    gemm_dual_k<<<(NKW + 63) / 64, 256, 0, stream>>>(kw1_bf, NKW, W5, bc2, out_kw, W7, Yb);
    gemm_dual_k<<<(NRT + 63) / 64, 256, 0, stream>>>(rt1_bf, NRT, W9, bl2c, out_rt, W6, Ya);
    gemm_single_k<<<(NRT + 63) / 64, 256, 0, stream>>>(rt1_bf, NRT, W8, Yc);
    fusedagg_k<2, 0, 0><<<nb_kw, 512, 0, stream>>>(out_kw, NKW, pairs_a, boff_a, Ya,
                                                   pairs_b, boff_b, Yb, out_kw, nullptr);
    fusedagg_k<1, 0, 0><<<nb_rt, 512, 0, stream>>>(out_rt, NRT, pairs_c, boff_c, Yc,
                                                   nullptr, nullptr, nullptr, out_rt, nullptr);
}

// Round 4
// 977.659 us; speedup vs baseline: 5.9519x; 5.9519x over previous
//
#include <hip/hip_runtime.h>

typedef __attribute__((ext_vector_type(8))) short bf16x8;
typedef __attribute__((ext_vector_type(4))) float f32x4;

static __device__ __forceinline__ unsigned short f2bf(float f) {
    unsigned int u = __float_as_uint(f);
    u += 0x7fffu + ((u >> 16) & 1u);   // round-to-nearest-even
    return (unsigned short)(u >> 16);
}
static __device__ __forceinline__ float bf2f(unsigned short h) {
    return __uint_as_float(((unsigned int)h) << 16);
}

#define BSH 6
#define BUCKET 64
#define NBMAX 1600
#define CHSH 13   // source chunk = src >> 13  (8192 rows = 2 MB bf16)

// ---------------- misc ----------------

__global__ void zero_k(int* p, int n) {
    int i = blockIdx.x * 256 + threadIdx.x;
    if (i < n) p[i] = 0;
}

struct PrepArgs {
    const float* W[10];
    const float* Wa[10];
    const float* b1a; const float* b1b; const float* b2a; const float* b2b;
};

// blocks 0..639: transpose+bf16 (slot = blk>>6); block 640: combined biases
__global__ void prep_k(PrepArgs pa, unsigned short* __restrict__ Wt,
                       float* __restrict__ bc1, float* __restrict__ bc2) {
    int blk = blockIdx.x;
    if (blk < 640) {
        int slot = blk >> 6;
        int i = ((blk & 63) << 8) + threadIdx.x;   // 0..16383
        int k = i >> 7, n = i & 127;
        float v = pa.W[slot][i];
        const float* w2 = pa.Wa[slot];
        if (w2) v += w2[i];
        Wt[slot * 16384 + n * 128 + k] = f2bf(v);
    } else {
        int t = threadIdx.x;
        if (t < 128) bc1[t] = pa.b1a[t] + pa.b1b[t];
        else bc2[t - 128] = pa.b2a[t - 128] + pa.b2b[t - 128];
    }
}

__global__ void f2bf_vec_k(const float* __restrict__ x, unsigned short* __restrict__ y, int n4) {
    int i = blockIdx.x * 256 + threadIdx.x;
    if (i < n4) {
        float4 v = ((const float4*)x)[i];
        ushort4 o;
        o.x = f2bf(v.x); o.y = f2bf(v.y); o.z = f2bf(v.z); o.w = f2bf(v.w);
        ((ushort4*)y)[i] = o;
    }
}

// ---------------- bucket build ----------------

__global__ void bhist_k(const int* __restrict__ dst, int E, int* __restrict__ bcnt, int nb) {
    __shared__ int h[NBMAX];
    for (int i = threadIdx.x; i < nb; i += 256) h[i] = 0;
    __syncthreads();
    for (int e = blockIdx.x * 256 + threadIdx.x; e < E; e += gridDim.x * 256)
        atomicAdd(&h[dst[e] >> BSH], 1);
    __syncthreads();
    for (int i = threadIdx.x; i < nb; i += 256)
        if (h[i]) atomicAdd(&bcnt[i], h[i]);
}

// single block, 1024 threads; exclusive scan of bcnt[0..nb) -> boff[0..nb]; zero bcur
__global__ void bscan_k(const int* __restrict__ bcnt, int nb, int* __restrict__ boff,
                        int* __restrict__ bcur) {
    __shared__ int s[1024];
    int t = threadIdx.x;
    int e0 = 2 * t, e1 = 2 * t + 1;
    int v0 = (e0 < nb) ? bcnt[e0] : 0;
    int v1 = (e1 < nb) ? bcnt[e1] : 0;
    s[t] = v0 + v1;
    __syncthreads();
    for (int o = 1; o < 1024; o <<= 1) {
        int x = (t >= o) ? s[t - o] : 0;
        __syncthreads();
        s[t] += x;
        __syncthreads();
    }
    int P = s[t] - (v0 + v1);
    if (e0 <= nb) { boff[e0] = P; if (e0 < nb) bcur[e0] = 0; }
    if (e1 <= nb) { boff[e1] = P + v0; if (e1 < nb) bcur[e1] = 0; }
}

// each block: 8192-edge chunk; privatized bucket scatter of packed pairs
__global__ __launch_bounds__(256) void bscatter_k(const int* __restrict__ src,
                                                  const int* __restrict__ dst, int E,
                                                  const int* __restrict__ boff,
                                                  int* __restrict__ bcur,
                                                  unsigned* __restrict__ pairs, int nb) {
    __shared__ int h[NBMAX];
    __shared__ int base[NBMAX];
    int t = threadIdx.x;
    for (int i = t; i < nb; i += 256) h[i] = 0;
    __syncthreads();
    int e0 = blockIdx.x * 8192;
    for (int i = 0; i < 32; i++) {
        int e = e0 + i * 256 + t;
        if (e < E) atomicAdd(&h[dst[e] >> BSH], 1);
    }
    __syncthreads();
    for (int i = t; i < nb; i += 256) {
        int c = h[i];
        base[i] = c ? (boff[i] + atomicAdd(&bcur[i], c)) : 0;
    }
    __syncthreads();
    for (int i = t; i < nb; i += 256) h[i] = 0;
    __syncthreads();
    for (int i = 0; i < 32; i++) {
        int e = e0 + i * 256 + t;
        if (e < E) {
            int d = dst[e];
            int b = d >> BSH;
            int pos = base[b] + atomicAdd(&h[b], 1);
            pairs[pos] = ((unsigned)(d & (BUCKET - 1)) << 17) | (unsigned)src[e];
        }
    }
}

// ---------------- per-bucket counting sort ----------------
// key bin = (chunk<<6) | ((dloc&15)<<2) | (dloc>>4); group g (=thread t) = 4 bins.
// Outputs: spairs (sorted), goff[b*256+g] (group start offsets), invd[dst] (1/cnt).
__global__ __launch_bounds__(256) void sortb_k(const unsigned* __restrict__ pairs,
                                               const int* __restrict__ boff,
                                               unsigned* __restrict__ spairs,
                                               int* __restrict__ goff,
                                               float* __restrict__ invd,
                                               int Ndst, int nch, int Etot) {
    __shared__ int cnt[1024];
    __shared__ int sc[256];
    int t = threadIdx.x;
    int b = blockIdx.x;
    for (int i = t; i < 1024; i += 256) cnt[i] = 0;
    __syncthreads();
    int j0 = boff[b], j1 = boff[b + 1];
    for (int j = j0 + t; j < j1; j += 256) {
        unsigned p = pairs[j];
        int d = (p >> 17) & 63, s = p & 0x1ffff;
        int bin = ((s >> CHSH) << 6) | ((d & 15) << 2) | (d >> 4);
        atomicAdd(&cnt[bin], 1);
    }
    __syncthreads();
    // per-row counts -> invd  (reads cnt only)
    if (t < 64) {
        int c = 0;
        for (int cc = 0; cc < nch; cc++) c += cnt[(cc << 6) | ((t & 15) << 2) | (t >> 4)];
        int dst = (b << BSH) + t;
        if (dst < Ndst) invd[dst] = 1.f / (float)(c > 0 ? c : 1);
    }
    int c0 = cnt[4 * t], c1 = cnt[4 * t + 1], c2 = cnt[4 * t + 2], c3 = cnt[4 * t + 3];
    int tot = c0 + c1 + c2 + c3;
    sc[t] = tot;
    __syncthreads();
    for (int o = 1; o < 256; o <<= 1) {
        int x = (t >= o) ? sc[t - o] : 0;
        __syncthreads();
        sc[t] += x;
        __syncthreads();
    }
    int base = j0 + sc[t] - tot;
    goff[b * 256 + t] = base;
    cnt[4 * t] = base;
    cnt[4 * t + 1] = base + c0;
    cnt[4 * t + 2] = base + c0 + c1;
    cnt[4 * t + 3] = base + c0 + c1 + c2;
    if (t == 0 && b == gridDim.x - 1) goff[gridDim.x * 256] = Etot;
    __syncthreads();
    for (int j = j0 + t; j < j1; j += 256) {
        unsigned p = pairs[j];
        int d = (p >> 17) & 63, s = p & 0x1ffff;
        int bin = ((s >> CHSH) << 6) | ((d & 15) << 2) | (d >> 4);
        int pos = atomicAdd(&cnt[bin], 1);
        spairs[pos] = p;
    }
}

// ---------------- MFMA GEMMs ----------------
// A-frag: lane l holds A[row0 + (l&15)][kc*32 + (l>>4)*8 + 0..7]
// C/D: lane l, reg j -> row (l>>4)*4 + j, col l&15   [m89]

__global__ __launch_bounds__(256) void gemm_single_k(const unsigned short* __restrict__ A, int N,
                                                     const unsigned short* __restrict__ Wt,
                                                     unsigned short* __restrict__ Cb) {
    int wv = threadIdx.x >> 6, lane = threadIdx.x & 63;
    int r16 = lane & 15, g = lane >> 4;
    int row0 = blockIdx.x * 64 + wv * 16;
    int arow = row0 + r16;
    int arow_c = arow < N ? arow : N - 1;
    const bf16x8* Arow = (const bf16x8*)(A + (size_t)arow_c * 128);
    bf16x8 af[4];
#pragma unroll
    for (int kc = 0; kc < 4; kc++) af[kc] = Arow[kc * 4 + g];
    f32x4 acc[8];
#pragma unroll
    for (int ct = 0; ct < 8; ct++) { f32x4 z = {0.f, 0.f, 0.f, 0.f}; acc[ct] = z; }
#pragma unroll
    for (int kc = 0; kc < 4; kc++) {
#pragma unroll
        for (int ct = 0; ct < 8; ct++) {
            bf16x8 bfrag = *(const bf16x8*)(Wt + ((ct * 16 + r16) << 7) + kc * 32 + g * 8);
            acc[ct] = __builtin_amdgcn_mfma_f32_16x16x32_bf16(af[kc], bfrag, acc[ct], 0, 0, 0);
        }
    }
#pragma unroll
    for (int ct = 0; ct < 8; ct++) {
        int col = ct * 16 + r16;
#pragma unroll
        for (int j = 0; j < 4; j++) {
            int r = row0 + g * 4 + j;
            if (r < N) Cb[(size_t)r * 128 + col] = f2bf(acc[ct][j]);
        }
    }
}

// C1 = A@W1 + bias1 (f32), C2 = A@W2 (bf16); shared A-fragments
__global__ __launch_bounds__(256) void gemm_dual_k(const unsigned short* __restrict__ A, int N,
                                                   const unsigned short* __restrict__ Wt1,
                                                   const float* __restrict__ bias1,
                                                   float* __restrict__ C1,
                                                   const unsigned short* __restrict__ Wt2,
                                                   unsigned short* __restrict__ C2) {
    int wv = threadIdx.x >> 6, lane = threadIdx.x & 63;
    int r16 = lane & 15, g = lane >> 4;
    int row0 = blockIdx.x * 64 + wv * 16;
    int arow = row0 + r16;
    int arow_c = arow < N ? arow : N - 1;
    const bf16x8* Arow = (const bf16x8*)(A + (size_t)arow_c * 128);
    bf16x8 af[4];
#pragma unroll
    for (int kc = 0; kc < 4; kc++) af[kc] = Arow[kc * 4 + g];
    f32x4 acc1[8], acc2[8];
#pragma unroll
    for (int ct = 0; ct < 8; ct++) {
        f32x4 z = {0.f, 0.f, 0.f, 0.f};
        acc1[ct] = z; acc2[ct] = z;
    }
#pragma unroll
    for (int kc = 0; kc < 4; kc++) {
#pragma unroll
        for (int ct = 0; ct < 8; ct++) {
            int wo = ((ct * 16 + r16) << 7) + kc * 32 + g * 8;
            bf16x8 b1 = *(const bf16x8*)(Wt1 + wo);
            acc1[ct] = __builtin_amdgcn_mfma_f32_16x16x32_bf16(af[kc], b1, acc1[ct], 0, 0, 0);
            bf16x8 b2 = *(const bf16x8*)(Wt2 + wo);
            acc2[ct] = __builtin_amdgcn_mfma_f32_16x16x32_bf16(af[kc], b2, acc2[ct], 0, 0, 0);
        }
    }
#pragma unroll
    for (int ct = 0; ct < 8; ct++) {
        int col = ct * 16 + r16;
        float b = bias1[col];
#pragma unroll
        for (int j = 0; j < 4; j++) {
            int r = row0 + g * 4 + j;
            if (r < N) {
                C1[(size_t)r * 128 + col] = acc1[ct][j] + b;
                C2[(size_t)r * 128 + col] = f2bf(acc2[ct][j]);
            }
        }
    }
}

// ---------------- bucket aggregation, atomic-free ----------------
// Block = one 64-dst bucket, 512 threads = 16 half-waves. Half-wave hw exclusively
// owns dlocs {hw, hw+16, hw+32, hw+48}; its edges per chunk are the contiguous run
// [goff[b*256 + c*16 + hw], goff[.. +1]). Rows accumulated in 4 VGPRs, flushed to
// LDS (swizzled: feature f=q*4+e at slot e*32+q) on row change. No float atomics.
template <int NREL, int RELU, int OUTBF16>
__global__ __launch_bounds__(512) void bagg_k(const float* __restrict__ Zin, int Ndst,
                                              const unsigned* __restrict__ sp0,
                                              const int* __restrict__ goff0,
                                              const float* __restrict__ invd0,
                                              const unsigned short* __restrict__ Y0, int nch0,
                                              const unsigned* __restrict__ sp1,
                                              const int* __restrict__ goff1,
                                              const float* __restrict__ invd1,
                                              const unsigned short* __restrict__ Y1, int nch1,
                                              float* __restrict__ OutF,
                                              unsigned short* __restrict__ OutB) {
    __shared__ float acc[BUCKET * 128];
    int t = threadIdx.x;
    int b = blockIdx.x;
    int dst0 = b << BSH;
    int nrow = Ndst - dst0; if (nrow > BUCKET) nrow = BUCKET;

    // init acc from Zin (swizzled)
    for (int c = t; c < BUCKET * 32; c += 512) {
        int r = c >> 5, m = c & 31;
        float4 z = make_float4(0.f, 0.f, 0.f, 0.f);
        if (r < nrow) z = ((const float4*)Zin)[(size_t)(dst0 + r) * 32 + m];
        acc[r * 128 + m] = z.x;
        acc[r * 128 + 32 + m] = z.y;
        acc[r * 128 + 64 + m] = z.z;
        acc[r * 128 + 96 + m] = z.w;
    }
    __syncthreads();

    int hw = t >> 5, q = t & 31;
#pragma unroll 1
    for (int rel = 0; rel < NREL; rel++) {
        const unsigned* sp = rel ? sp1 : sp0;
        const int* goff = rel ? goff1 : goff0;
        const float* invd = rel ? invd1 : invd0;
        const unsigned short* Y = rel ? Y1 : Y0;
        int nch = rel ? nch1 : nch0;
        float a0 = 0.f, a1 = 0.f, a2 = 0.f, a3 = 0.f;
        int curd = -1;
        float inv = 0.f;
#pragma unroll 1
        for (int c = 0; c < nch; c++) {
            int g = b * 256 + c * 16 + hw;
            int jg0 = goff[g], jg1 = goff[g + 1];
#pragma unroll 1
            for (int j = jg0; j < jg1; j++) {
                unsigned p = sp[j];
                int s = p & 0x1ffff;
                int d = (p >> 17) & 63;
                if (d != curd) {
                    if (curd >= 0) {
                        int ba = curd * 128 + q;
                        acc[ba] += a0; acc[ba + 32] += a1;
                        acc[ba + 64] += a2; acc[ba + 96] += a3;
                    }
                    curd = d;
                    a0 = a1 = a2 = a3 = 0.f;
                    inv = invd[dst0 + d];
                }
                ushort4 v = *(const ushort4*)(Y + ((size_t)s << 7) + (q << 2));
                a0 += bf2f(v.x) * inv;
                a1 += bf2f(v.y) * inv;
                a2 += bf2f(v.z) * inv;
                a3 += bf2f(v.w) * inv;
            }
        }
        if (curd >= 0) {
            int ba = curd * 128 + q;
            acc[ba] += a0; acc[ba + 32] += a1;
            acc[ba + 64] += a2; acc[ba + 96] += a3;
        }
    }
    __syncthreads();
    // finalize
    for (int c = t; c < BUCKET * 32; c += 512) {
        int r = c >> 5, m = c & 31;
        if (r < nrow) {
            float x0 = acc[r * 128 + m];
            float x1 = acc[r * 128 + 32 + m];
            float x2 = acc[r * 128 + 64 + m];
            float x3 = acc[r * 128 + 96 + m];
            if (RELU) {
                x0 = fmaxf(x0, 0.f); x1 = fmaxf(x1, 0.f);
                x2 = fmaxf(x2, 0.f); x3 = fmaxf(x3, 0.f);
            }
            size_t o = (size_t)(dst0 + r) * 128 + (m << 2);
            if (OUTBF16) {
                ushort4 ov;
                ov.x = f2bf(x0); ov.y = f2bf(x1); ov.z = f2bf(x2); ov.w = f2bf(x3);
                *(ushort4*)(OutB + o) = ov;
            } else {
                *(float4*)(OutF + o) = make_float4(x0, x1, x2, x3);
            }
        }
    }
}

// ---------------- launch ----------------

static inline size_t align256(size_t x) { return (x + 255) & ~size_t(255); }

extern "C" void kernel_launch(void* const* d_in, const int* in_sizes, int n_in,
                              void* d_out, int out_size, void* d_ws, size_t ws_size,
                              hipStream_t stream) {
    const float* x_kw = (const float*)d_in[0];
    const float* x_rt = (const float*)d_in[1];
    const int* src_a = (const int*)d_in[2];
    const int* dst_a = (const int*)d_in[3];
    const int* src_b = (const int*)d_in[4];
    const int* dst_b = (const int*)d_in[5];
    const int* src_c = (const int*)d_in[6];
    const int* dst_c = (const int*)d_in[7];
    const float *Wl1a = (const float*)d_in[8],  *bl1a = (const float*)d_in[9],  *Wr1a = (const float*)d_in[10];
    const float *Wl1b = (const float*)d_in[11], *bl1b = (const float*)d_in[12], *Wr1b = (const float*)d_in[13];
    const float *Wl1c = (const float*)d_in[14], *bl1c = (const float*)d_in[15], *Wr1c = (const float*)d_in[16];
    const float *Wl2a = (const float*)d_in[17], *bl2a = (const float*)d_in[18], *Wr2a = (const float*)d_in[19];
    const float *Wl2b = (const float*)d_in[20], *bl2b = (const float*)d_in[21], *Wr2b = (const float*)d_in[22];
    const float *Wl2c = (const float*)d_in[23], *bl2c = (const float*)d_in[24], *Wr2c = (const float*)d_in[25];

    const int NKW = in_sizes[0] / 128;
    const int NRT = in_sizes[1] / 128;
    const int EA = in_sizes[2], EB = in_sizes[4], EC = in_sizes[6];
    const int nb_kw = (NKW + BUCKET - 1) / BUCKET;
    const int nb_rt = (NRT + BUCKET - 1) / BUCKET;
    const int ncha = (NRT + (1 << CHSH) - 1) >> CHSH;   // src space = rt
    const int nchb = (NKW + (1 << CHSH) - 1) >> CHSH;   // src space = kw
    const int nchc = ncha;

    char* ws = (char*)d_ws;
    size_t off = 0;
    auto alloc = [&](size_t bytes) -> char* {
        off = align256(off);
        char* p = ws + off;
        off += bytes;
        return p;
    };
    unsigned short* Wt = (unsigned short*)alloc(10 * 16384 * 2);
    float* bc1 = (float*)alloc(128 * 4);
    float* bc2 = (float*)alloc(128 * 4);
    int* bcnt = (int*)alloc(NBMAX * 4);
    int* bcur = (int*)alloc(NBMAX * 4);
    int* boff_a = (int*)alloc((NBMAX + 1) * 4);
    int* boff_b = (int*)alloc((NBMAX + 1) * 4);
    int* boff_c = (int*)alloc((NBMAX + 1) * 4);
    int* goff_a = (int*)alloc(((size_t)nb_kw * 256 + 1) * 4);
    int* goff_b = (int*)alloc(((size_t)nb_kw * 256 + 1) * 4);
    int* goff_c = (int*)alloc(((size_t)nb_rt * 256 + 1) * 4);
    float* invd_a = (float*)alloc((size_t)NKW * 4);
    float* invd_b = (float*)alloc((size_t)NKW * 4);
    float* invd_c = (float*)alloc((size_t)NRT * 4);
    unsigned* pairs_a = (unsigned*)alloc((size_t)EA * 4);
    unsigned* pairs_b = (unsigned*)alloc((size_t)EB * 4);
    unsigned* pairs_c = (unsigned*)alloc((size_t)EC * 4);
    unsigned* sp_a = (unsigned*)alloc((size_t)EA * 4);
    unsigned* sp_b = (unsigned*)alloc((size_t)EB * 4);
    unsigned* sp_c = (unsigned*)alloc((size_t)EC * 4);
    unsigned short* xkw_bf = (unsigned short*)alloc((size_t)NKW * 128 * 2);
    unsigned short* xrt_bf = (unsigned short*)alloc((size_t)NRT * 128 * 2);
    unsigned short* Yb = (unsigned short*)alloc((size_t)NKW * 128 * 2);
    (void)ws_size;
    // aliases: pairs_* dead after sorts; Y buffers written by GEMMs afterwards
    unsigned short* Ya = (unsigned short*)pairs_b;   // 5.12 MB <= 6.4 MB
    unsigned short* Yc = (unsigned short*)pairs_a;   // 5.12 MB <= 6.4 MB
    unsigned short* kw1_bf = xkw_bf;                 // x_kw bf16 dead after L1 GEMMs
    unsigned short* rt1_bf = xrt_bf;

    float* out_kw = (float*)d_out;
    float* out_rt = out_kw + (size_t)NKW * 128;

    // ---- prep: weights (transposed bf16) + combined biases ----
    PrepArgs pa;
    pa.W[0] = Wr1a; pa.Wa[0] = Wr1b;
    pa.W[1] = Wl1a; pa.Wa[1] = nullptr;
    pa.W[2] = Wl1b; pa.Wa[2] = nullptr;
    pa.W[3] = Wl1c; pa.Wa[3] = nullptr;
    pa.W[4] = Wr1c; pa.Wa[4] = nullptr;
    pa.W[5] = Wr2a; pa.Wa[5] = Wr2b;
    pa.W[6] = Wl2a; pa.Wa[6] = nullptr;
    pa.W[7] = Wl2b; pa.Wa[7] = nullptr;
    pa.W[8] = Wl2c; pa.Wa[8] = nullptr;
    pa.W[9] = Wr2c; pa.Wa[9] = nullptr;
    pa.b1a = bl1a; pa.b1b = bl1b; pa.b2a = bl2a; pa.b2b = bl2b;
    prep_k<<<641, 256, 0, stream>>>(pa, Wt, bc1, bc2);
    unsigned short* W0 = Wt + 0 * 16384;
    unsigned short* W1 = Wt + 1 * 16384;
    unsigned short* W2 = Wt + 2 * 16384;
    unsigned short* W3 = Wt + 3 * 16384;
    unsigned short* W4 = Wt + 4 * 16384;
    unsigned short* W5 = Wt + 5 * 16384;
    unsigned short* W6 = Wt + 6 * 16384;
    unsigned short* W7 = Wt + 7 * 16384;
    unsigned short* W8 = Wt + 8 * 16384;
    unsigned short* W9 = Wt + 9 * 16384;

    f2bf_vec_k<<<(NKW * 32 + 255) / 256, 256, 0, stream>>>(x_kw, xkw_bf, NKW * 32);
    f2bf_vec_k<<<(NRT * 32 + 255) / 256, 256, 0, stream>>>(x_rt, xrt_bf, NRT * 32);

    // ---- bucket build + sort per relation ----
    auto build = [&](const int* src, const int* dst, int E, int nb, int* boff,
                     unsigned* pairs, unsigned* sp, int* goff, float* invd, int Ndst, int nch) {
        zero_k<<<(nb + 255) / 256, 256, 0, stream>>>(bcnt, nb);
        bhist_k<<<256, 256, 0, stream>>>(dst, E, bcnt, nb);
        bscan_k<<<1, 1024, 0, stream>>>(bcnt, nb, boff, bcur);
        bscatter_k<<<(E + 8191) / 8192, 256, 0, stream>>>(src, dst, E, boff, bcur, pairs, nb);
        sortb_k<<<nb, 256, 0, stream>>>(pairs, boff, sp, goff, invd, Ndst, nch, E);
    };
    build(src_a, dst_a, EA, nb_kw, boff_a, pairs_a, sp_a, goff_a, invd_a, NKW, ncha);
    build(src_b, dst_b, EB, nb_kw, boff_b, pairs_b, sp_b, goff_b, invd_b, NKW, nchb);
    build(src_c, dst_c, EC, nb_rt, boff_c, pairs_c, sp_c, goff_c, invd_c, NRT, nchc);

    // ---- layer 1 ----
    gemm_dual_k<<<(NKW + 63) / 64, 256, 0, stream>>>(xkw_bf, NKW, W0, bc1, out_kw, W2, Yb);
    gemm_dual_k<<<(NRT + 63) / 64, 256, 0, stream>>>(xrt_bf, NRT, W4, bl1c, out_rt, W1, Ya);
    gemm_single_k<<<(NRT + 63) / 64, 256, 0, stream>>>(xrt_bf, NRT, W3, Yc);
    bagg_k<2, 1, 1><<<nb_kw, 512, 0, stream>>>(out_kw, NKW,
                                               sp_a, goff_a, invd_a, Ya, ncha,
                                               sp_b, goff_b, invd_b, Yb, nchb,
                                               nullptr, kw1_bf);
    bagg_k<1, 1, 1><<<nb_rt, 512, 0, stream>>>(out_rt, NRT,
                                               sp_c, goff_c, invd_c, Yc, nchc,
                                               nullptr, nullptr, nullptr, nullptr, 0,
                                               nullptr, rt1_bf);

    // ---- layer 2 ----
    gemm_dual_k<<<(NKW + 63) / 64, 256, 0, stream>>>(kw1_bf, NKW, W5, bc2, out_kw, W7, Yb);
    gemm_dual_k<<<(NRT + 63) / 64, 256, 0, stream>>>(rt1_bf, NRT, W9, bl2c, out_rt, W6, Ya);
    gemm_single_k<<<(NRT + 63) / 64, 256, 0, stream>>>(rt1_bf, NRT, W8, Yc);
    bagg_k<2, 0, 0><<<nb_kw, 512, 0, stream>>>(out_kw, NKW,
                                               sp_a, goff_a, invd_a, Ya, ncha,
                                               sp_b, goff_b, invd_b, Yb, nchb,
                                               out_kw, nullptr);
    bagg_k<1, 0, 0><<<nb_rt, 512, 0, stream>>>(out_rt, NRT,
                                               sp_c, goff_c, invd_c, Yc, nchc,
                                               nullptr, nullptr, nullptr, nullptr, 0,
                                               out_rt, nullptr);
}

// Round 5
// 717.107 us; speedup vs baseline: 8.1144x; 1.3633x over previous
//
#include <hip/hip_runtime.h>

typedef __attribute__((ext_vector_type(8))) short bf16x8;
typedef __attribute__((ext_vector_type(4))) float f32x4;

static __device__ __forceinline__ unsigned short f2bf(float f) {
    unsigned int u = __float_as_uint(f);
    u += 0x7fffu + ((u >> 16) & 1u);   // round-to-nearest-even
    return (unsigned short)(u >> 16);
}
static __device__ __forceinline__ float bf2f(unsigned short h) {
    return __uint_as_float(((unsigned int)h) << 16);
}

#define BSH 6
#define BUCKET 64
#define NBMAX 1600
#define CHSH 13   // source chunk = src >> 13 (8192 rows = 2 MB bf16); clamped to 15

// ---------------- misc ----------------

__global__ void zero_k(int* p, int n) {
    int i = blockIdx.x * 256 + threadIdx.x;
    if (i < n) p[i] = 0;
}

struct PrepArgs {
    const float* W[10];
    const float* Wa[10];
    const float* b1a; const float* b1b; const float* b2a; const float* b2b;
};

// blocks 0..639: transpose+bf16 (slot = blk>>6); block 640: combined biases
__global__ void prep_k(PrepArgs pa, unsigned short* __restrict__ Wt,
                       float* __restrict__ bc1, float* __restrict__ bc2) {
    int blk = blockIdx.x;
    if (blk < 640) {
        int slot = blk >> 6;
        int i = ((blk & 63) << 8) + threadIdx.x;   // 0..16383
        int k = i >> 7, n = i & 127;
        float v = pa.W[slot][i];
        const float* w2 = pa.Wa[slot];
        if (w2) v += w2[i];
        Wt[slot * 16384 + n * 128 + k] = f2bf(v);
    } else {
        int t = threadIdx.x;
        if (t < 128) bc1[t] = pa.b1a[t] + pa.b1b[t];
        else bc2[t - 128] = pa.b2a[t - 128] + pa.b2b[t - 128];
    }
}

__global__ void f2bf_vec_k(const float* __restrict__ x, unsigned short* __restrict__ y, int n4) {
    int i = blockIdx.x * 256 + threadIdx.x;
    if (i < n4) {
        float4 v = ((const float4*)x)[i];
        ushort4 o;
        o.x = f2bf(v.x); o.y = f2bf(v.y); o.z = f2bf(v.z); o.w = f2bf(v.w);
        ((ushort4*)y)[i] = o;
    }
}

// ---------------- bucket build ----------------

__global__ void bhist_k(const int* __restrict__ dst, int E, int* __restrict__ bcnt, int nb) {
    __shared__ int h[NBMAX];
    for (int i = threadIdx.x; i < nb; i += 256) h[i] = 0;
    __syncthreads();
    for (int e = blockIdx.x * 256 + threadIdx.x; e < E; e += gridDim.x * 256)
        atomicAdd(&h[dst[e] >> BSH], 1);
    __syncthreads();
    for (int i = threadIdx.x; i < nb; i += 256)
        if (h[i]) atomicAdd(&bcnt[i], h[i]);
}

// single block, 1024 threads; exclusive scan of bcnt[0..nb) -> boff[0..nb]; zero bcur
__global__ void bscan_k(const int* __restrict__ bcnt, int nb, int* __restrict__ boff,
                        int* __restrict__ bcur) {
    __shared__ int s[1024];
    int t = threadIdx.x;
    int e0 = 2 * t, e1 = 2 * t + 1;
    int v0 = (e0 < nb) ? bcnt[e0] : 0;
    int v1 = (e1 < nb) ? bcnt[e1] : 0;
    s[t] = v0 + v1;
    __syncthreads();
    for (int o = 1; o < 1024; o <<= 1) {
        int x = (t >= o) ? s[t - o] : 0;
        __syncthreads();
        s[t] += x;
        __syncthreads();
    }
    int P = s[t] - (v0 + v1);
    if (e0 <= nb) { boff[e0] = P; if (e0 < nb) bcur[e0] = 0; }
    if (e1 <= nb) { boff[e1] = P + v0; if (e1 < nb) bcur[e1] = 0; }
}

// each block: 8192-edge chunk; privatized bucket scatter of packed pairs
__global__ __launch_bounds__(256) void bscatter_k(const int* __restrict__ src,
                                                  const int* __restrict__ dst, int E,
                                                  const int* __restrict__ boff,
                                                  int* __restrict__ bcur,
                                                  unsigned* __restrict__ pairs, int nb) {
    __shared__ int h[NBMAX];
    __shared__ int base[NBMAX];
    int t = threadIdx.x;
    for (int i = t; i < nb; i += 256) h[i] = 0;
    __syncthreads();
    int e0 = blockIdx.x * 8192;
    for (int i = 0; i < 32; i++) {
        int e = e0 + i * 256 + t;
        if (e < E) atomicAdd(&h[dst[e] >> BSH], 1);
    }
    __syncthreads();
    for (int i = t; i < nb; i += 256) {
        int c = h[i];
        base[i] = c ? (boff[i] + atomicAdd(&bcur[i], c)) : 0;
    }
    __syncthreads();
    for (int i = t; i < nb; i += 256) h[i] = 0;
    __syncthreads();
    for (int i = 0; i < 32; i++) {
        int e = e0 + i * 256 + t;
        if (e < E) {
            int d = dst[e];
            int b = d >> BSH;
            int pos = base[b] + atomicAdd(&h[b], 1);
            pairs[pos] = ((unsigned)(d & (BUCKET - 1)) << 17) | (unsigned)src[e];
        }
    }
}

// ---------------- per-bucket counting sort (d-major) ----------------
// bin = ((d&15)<<6) | ((d>>4)<<4) | min(src>>CHSH,15). Sub-run (16 bins) =
// one (half-wave, d-row) pair: contiguous edges, d fixed. spairs stores src only.
// goff[b*64 + (hw*4+r)] = sub-run starts; invd[dst] = 1/cnt.
__global__ __launch_bounds__(256) void sortb_k(const unsigned* __restrict__ pairs,
                                               const int* __restrict__ boff,
                                               unsigned* __restrict__ ssrc,
                                               int* __restrict__ goff,
                                               float* __restrict__ invd,
                                               int Ndst, int Etot) {
    __shared__ int cnt[1024];
    __shared__ int sc[256];
    int t = threadIdx.x;
    int b = blockIdx.x;
    for (int i = t; i < 1024; i += 256) cnt[i] = 0;
    __syncthreads();
    int j0 = boff[b], j1 = boff[b + 1];
    for (int j = j0 + t; j < j1; j += 256) {
        unsigned p = pairs[j];
        int d = (p >> 17) & 63;
        int ch = (int)((p & 0x1ffffu) >> CHSH); if (ch > 15) ch = 15;
        int bin = ((d & 15) << 6) | ((d >> 4) << 4) | ch;
        atomicAdd(&cnt[bin], 1);
    }
    __syncthreads();
    // per-dst-row counts -> invd
    if (t < 64) {
        int b0 = ((t & 15) << 6) | ((t >> 4) << 4);
        int c = 0;
#pragma unroll
        for (int i = 0; i < 16; i++) c += cnt[b0 + i];
        int dd = (b << BSH) + t;
        if (dd < Ndst) invd[dd] = 1.f / (float)(c > 0 ? c : 1);
    }
    int c0 = cnt[4 * t], c1 = cnt[4 * t + 1], c2 = cnt[4 * t + 2], c3 = cnt[4 * t + 3];
    int tot = c0 + c1 + c2 + c3;
    sc[t] = tot;
    __syncthreads();
    for (int o = 1; o < 256; o <<= 1) {
        int x = (t >= o) ? sc[t - o] : 0;
        __syncthreads();
        sc[t] += x;
        __syncthreads();
    }
    int base = j0 + sc[t] - tot;
    if ((t & 3) == 0) goff[b * 64 + (t >> 2)] = base;
    cnt[4 * t] = base;
    cnt[4 * t + 1] = base + c0;
    cnt[4 * t + 2] = base + c0 + c1;
    cnt[4 * t + 3] = base + c0 + c1 + c2;
    if (t == 0 && b == gridDim.x - 1) goff[gridDim.x * 64] = Etot;
    __syncthreads();
    for (int j = j0 + t; j < j1; j += 256) {
        unsigned p = pairs[j];
        int d = (p >> 17) & 63;
        int ch = (int)((p & 0x1ffffu) >> CHSH); if (ch > 15) ch = 15;
        int bin = ((d & 15) << 6) | ((d >> 4) << 4) | ch;
        int pos = atomicAdd(&cnt[bin], 1);
        ssrc[pos] = p & 0x1ffffu;
    }
}

// ---------------- MFMA GEMMs ----------------
// A-frag: lane l holds A[row0 + (l&15)][kc*32 + (l>>4)*8 + 0..7]
// C/D: lane l, reg j -> row (l>>4)*4 + j, col l&15   [m89]

__global__ __launch_bounds__(256) void gemm_single_k(const unsigned short* __restrict__ A, int N,
                                                     const unsigned short* __restrict__ Wt,
                                                     unsigned short* __restrict__ Cb) {
    int wv = threadIdx.x >> 6, lane = threadIdx.x & 63;
    int r16 = lane & 15, g = lane >> 4;
    int row0 = blockIdx.x * 64 + wv * 16;
    int arow = row0 + r16;
    int arow_c = arow < N ? arow : N - 1;
    const bf16x8* Arow = (const bf16x8*)(A + (size_t)arow_c * 128);
    bf16x8 af[4];
#pragma unroll
    for (int kc = 0; kc < 4; kc++) af[kc] = Arow[kc * 4 + g];
    f32x4 acc[8];
#pragma unroll
    for (int ct = 0; ct < 8; ct++) { f32x4 z = {0.f, 0.f, 0.f, 0.f}; acc[ct] = z; }
#pragma unroll
    for (int kc = 0; kc < 4; kc++) {
#pragma unroll
        for (int ct = 0; ct < 8; ct++) {
            bf16x8 bfrag = *(const bf16x8*)(Wt + ((ct * 16 + r16) << 7) + kc * 32 + g * 8);
            acc[ct] = __builtin_amdgcn_mfma_f32_16x16x32_bf16(af[kc], bfrag, acc[ct], 0, 0, 0);
        }
    }
#pragma unroll
    for (int ct = 0; ct < 8; ct++) {
        int col = ct * 16 + r16;
#pragma unroll
        for (int j = 0; j < 4; j++) {
            int r = row0 + g * 4 + j;
            if (r < N) Cb[(size_t)r * 128 + col] = f2bf(acc[ct][j]);
        }
    }
}

// C1 = A@W1 + bias1 (f32), C2 = A@W2 (bf16); shared A-fragments
__global__ __launch_bounds__(256) void gemm_dual_k(const unsigned short* __restrict__ A, int N,
                                                   const unsigned short* __restrict__ Wt1,
                                                   const float* __restrict__ bias1,
                                                   float* __restrict__ C1,
                                                   const unsigned short* __restrict__ Wt2,
                                                   unsigned short* __restrict__ C2) {
    int wv = threadIdx.x >> 6, lane = threadIdx.x & 63;
    int r16 = lane & 15, g = lane >> 4;
    int row0 = blockIdx.x * 64 + wv * 16;
    int arow = row0 + r16;
    int arow_c = arow < N ? arow : N - 1;
    const bf16x8* Arow = (const bf16x8*)(A + (size_t)arow_c * 128);
    bf16x8 af[4];
#pragma unroll
    for (int kc = 0; kc < 4; kc++) af[kc] = Arow[kc * 4 + g];
    f32x4 acc1[8], acc2[8];
#pragma unroll
    for (int ct = 0; ct < 8; ct++) {
        f32x4 z = {0.f, 0.f, 0.f, 0.f};
        acc1[ct] = z; acc2[ct] = z;
    }
#pragma unroll
    for (int kc = 0; kc < 4; kc++) {
#pragma unroll
        for (int ct = 0; ct < 8; ct++) {
            int wo = ((ct * 16 + r16) << 7) + kc * 32 + g * 8;
            bf16x8 b1 = *(const bf16x8*)(Wt1 + wo);
            acc1[ct] = __builtin_amdgcn_mfma_f32_16x16x32_bf16(af[kc], b1, acc1[ct], 0, 0, 0);
            bf16x8 b2 = *(const bf16x8*)(Wt2 + wo);
            acc2[ct] = __builtin_amdgcn_mfma_f32_16x16x32_bf16(af[kc], b2, acc2[ct], 0, 0, 0);
        }
    }
#pragma unroll
    for (int ct = 0; ct < 8; ct++) {
        int col = ct * 16 + r16;
        float b = bias1[col];
#pragma unroll
        for (int j = 0; j < 4; j++) {
            int r = row0 + g * 4 + j;
            if (r < N) {
                C1[(size_t)r * 128 + col] = acc1[ct][j] + b;
                C2[(size_t)r * 128 + col] = f2bf(acc2[ct][j]);
            }
        }
    }
}

// ---------------- bucket aggregation, atomic-free, batch-8 MLP ----------------
// Block = one 64-dst bucket, 512 threads = 16 half-waves. Half-wave hw owns dst
// rows {hw, hw+16, hw+32, hw+48}; each row's edges are ONE contiguous sub-run
// (d-major sort), gathered with 8 loads in flight, accumulated raw in 4 VGPRs,
// scaled once and flushed non-atomically to the exclusive LDS slot.
template <int NREL, int RELU, int OUTBF16>
__global__ __launch_bounds__(512) void bagg_k(const float* __restrict__ Zin, int Ndst,
                                              const unsigned* __restrict__ sp0,
                                              const int* __restrict__ goff0,
                                              const float* __restrict__ invd0,
                                              const unsigned short* __restrict__ Y0,
                                              const unsigned* __restrict__ sp1,
                                              const int* __restrict__ goff1,
                                              const float* __restrict__ invd1,
                                              const unsigned short* __restrict__ Y1,
                                              float* __restrict__ OutF,
                                              unsigned short* __restrict__ OutB) {
    __shared__ float acc[BUCKET * 128];
    int t = threadIdx.x;
    int b = blockIdx.x;
    int dst0 = b << BSH;
    int nrow = Ndst - dst0; if (nrow > BUCKET) nrow = BUCKET;

    // init acc from Zin (swizzled: feature 4m+e at r*128 + e*32 + m)
    for (int c = t; c < BUCKET * 32; c += 512) {
        int r = c >> 5, m = c & 31;
        float4 z = make_float4(0.f, 0.f, 0.f, 0.f);
        if (r < nrow) z = ((const float4*)Zin)[(size_t)(dst0 + r) * 32 + m];
        acc[r * 128 + m] = z.x;
        acc[r * 128 + 32 + m] = z.y;
        acc[r * 128 + 64 + m] = z.z;
        acc[r * 128 + 96 + m] = z.w;
    }
    __syncthreads();

    int hw = t >> 5, q = t & 31;
#pragma unroll 1
    for (int rel = 0; rel < NREL; rel++) {
        const unsigned* sp = rel ? sp1 : sp0;
        const int* goff = rel ? goff1 : goff0;
        const float* invd = rel ? invd1 : invd0;
        const unsigned short* Y = rel ? Y1 : Y0;
#pragma unroll 1
        for (int r = 0; r < 4; r++) {
            int g = b * 64 + hw * 4 + r;
            int jg0 = goff[g], jg1 = goff[g + 1];
            if (jg0 >= jg1) continue;
            int d = (r << 4) | hw;
            float a0 = 0.f, a1 = 0.f, a2 = 0.f, a3 = 0.f;
#pragma unroll 1
            for (int j = jg0; j < jg1; j += 8) {
                int ji[8];
                ushort4 v[8];
#pragma unroll
                for (int k = 0; k < 8; k++) {
                    int jj = j + k;
                    ji[k] = jj < jg1 ? jj : jg1 - 1;
                }
#pragma unroll
                for (int k = 0; k < 8; k++) {
                    int s = (int)sp[ji[k]];
                    v[k] = *(const ushort4*)(Y + ((size_t)s << 7) + (q << 2));
                }
#pragma unroll
                for (int k = 0; k < 8; k++) {
                    if (j + k < jg1) {
                        a0 += bf2f(v[k].x);
                        a1 += bf2f(v[k].y);
                        a2 += bf2f(v[k].z);
                        a3 += bf2f(v[k].w);
                    }
                }
            }
            float inv = invd[dst0 + d];
            int ba = d * 128 + q;
            acc[ba] += a0 * inv;
            acc[ba + 32] += a1 * inv;
            acc[ba + 64] += a2 * inv;
            acc[ba + 96] += a3 * inv;
        }
    }
    __syncthreads();
    // finalize
    for (int c = t; c < BUCKET * 32; c += 512) {
        int r = c >> 5, m = c & 31;
        if (r < nrow) {
            float x0 = acc[r * 128 + m];
            float x1 = acc[r * 128 + 32 + m];
            float x2 = acc[r * 128 + 64 + m];
            float x3 = acc[r * 128 + 96 + m];
            if (RELU) {
                x0 = fmaxf(x0, 0.f); x1 = fmaxf(x1, 0.f);
                x2 = fmaxf(x2, 0.f); x3 = fmaxf(x3, 0.f);
            }
            size_t o = (size_t)(dst0 + r) * 128 + (m << 2);
            if (OUTBF16) {
                ushort4 ov;
                ov.x = f2bf(x0); ov.y = f2bf(x1); ov.z = f2bf(x2); ov.w = f2bf(x3);
                *(ushort4*)(OutB + o) = ov;
            } else {
                *(float4*)(OutF + o) = make_float4(x0, x1, x2, x3);
            }
        }
    }
}

// ---------------- launch ----------------

static inline size_t align256(size_t x) { return (x + 255) & ~size_t(255); }

extern "C" void kernel_launch(void* const* d_in, const int* in_sizes, int n_in,
                              void* d_out, int out_size, void* d_ws, size_t ws_size,
                              hipStream_t stream) {
    const float* x_kw = (const float*)d_in[0];
    const float* x_rt = (const float*)d_in[1];
    const int* src_a = (const int*)d_in[2];
    const int* dst_a = (const int*)d_in[3];
    const int* src_b = (const int*)d_in[4];
    const int* dst_b = (const int*)d_in[5];
    const int* src_c = (const int*)d_in[6];
    const int* dst_c = (const int*)d_in[7];
    const float *Wl1a = (const float*)d_in[8],  *bl1a = (const float*)d_in[9],  *Wr1a = (const float*)d_in[10];
    const float *Wl1b = (const float*)d_in[11], *bl1b = (const float*)d_in[12], *Wr1b = (const float*)d_in[13];
    const float *Wl1c = (const float*)d_in[14], *bl1c = (const float*)d_in[15], *Wr1c = (const float*)d_in[16];
    const float *Wl2a = (const float*)d_in[17], *bl2a = (const float*)d_in[18], *Wr2a = (const float*)d_in[19];
    const float *Wl2b = (const float*)d_in[20], *bl2b = (const float*)d_in[21], *Wr2b = (const float*)d_in[22];
    const float *Wl2c = (const float*)d_in[23], *bl2c = (const float*)d_in[24], *Wr2c = (const float*)d_in[25];

    const int NKW = in_sizes[0] / 128;
    const int NRT = in_sizes[1] / 128;
    const int EA = in_sizes[2], EB = in_sizes[4], EC = in_sizes[6];
    const int nb_kw = (NKW + BUCKET - 1) / BUCKET;
    const int nb_rt = (NRT + BUCKET - 1) / BUCKET;

    char* ws = (char*)d_ws;
    size_t off = 0;
    auto alloc = [&](size_t bytes) -> char* {
        off = align256(off);
        char* p = ws + off;
        off += bytes;
        return p;
    };
    unsigned short* Wt = (unsigned short*)alloc(10 * 16384 * 2);
    float* bc1 = (float*)alloc(128 * 4);
    float* bc2 = (float*)alloc(128 * 4);
    int* bcnt = (int*)alloc(NBMAX * 4);
    int* bcur = (int*)alloc(NBMAX * 4);
    int* boff_a = (int*)alloc((NBMAX + 1) * 4);
    int* boff_b = (int*)alloc((NBMAX + 1) * 4);
    int* boff_c = (int*)alloc((NBMAX + 1) * 4);
    int* goff_a = (int*)alloc(((size_t)nb_kw * 64 + 1) * 4);
    int* goff_b = (int*)alloc(((size_t)nb_kw * 64 + 1) * 4);
    int* goff_c = (int*)alloc(((size_t)nb_rt * 64 + 1) * 4);
    float* invd_a = (float*)alloc((size_t)NKW * 4);
    float* invd_b = (float*)alloc((size_t)NKW * 4);
    float* invd_c = (float*)alloc((size_t)NRT * 4);
    unsigned* pairs_a = (unsigned*)alloc((size_t)EA * 4);
    unsigned* pairs_b = (unsigned*)alloc((size_t)EB * 4);
    unsigned* pairs_c = (unsigned*)alloc((size_t)EC * 4);
    unsigned* sp_a = (unsigned*)alloc((size_t)EA * 4);
    unsigned* sp_b = (unsigned*)alloc((size_t)EB * 4);
    unsigned* sp_c = (unsigned*)alloc((size_t)EC * 4);
    unsigned short* xkw_bf = (unsigned short*)alloc((size_t)NKW * 128 * 2);
    unsigned short* xrt_bf = (unsigned short*)alloc((size_t)NRT * 128 * 2);
    unsigned short* Yb = (unsigned short*)alloc((size_t)NKW * 128 * 2);
    (void)ws_size;
    // aliases: pairs_* dead after sorts; Y buffers written by GEMMs afterwards
    unsigned short* Ya = (unsigned short*)pairs_b;   // 5.12 MB <= 6.4 MB
    unsigned short* Yc = (unsigned short*)pairs_a;   // 5.12 MB <= 6.4 MB
    unsigned short* kw1_bf = xkw_bf;                 // x_kw bf16 dead after L1 GEMMs
    unsigned short* rt1_bf = xrt_bf;

    float* out_kw = (float*)d_out;
    float* out_rt = out_kw + (size_t)NKW * 128;

    // ---- prep: weights (transposed bf16) + combined biases ----
    PrepArgs pa;
    pa.W[0] = Wr1a; pa.Wa[0] = Wr1b;
    pa.W[1] = Wl1a; pa.Wa[1] = nullptr;
    pa.W[2] = Wl1b; pa.Wa[2] = nullptr;
    pa.W[3] = Wl1c; pa.Wa[3] = nullptr;
    pa.W[4] = Wr1c; pa.Wa[4] = nullptr;
    pa.W[5] = Wr2a; pa.Wa[5] = Wr2b;
    pa.W[6] = Wl2a; pa.Wa[6] = nullptr;
    pa.W[7] = Wl2b; pa.Wa[7] = nullptr;
    pa.W[8] = Wl2c; pa.Wa[8] = nullptr;
    pa.W[9] = Wr2c; pa.Wa[9] = nullptr;
    pa.b1a = bl1a; pa.b1b = bl1b; pa.b2a = bl2a; pa.b2b = bl2b;
    prep_k<<<641, 256, 0, stream>>>(pa, Wt, bc1, bc2);
    unsigned short* W0 = Wt + 0 * 16384;
    unsigned short* W1 = Wt + 1 * 16384;
    unsigned short* W2 = Wt + 2 * 16384;
    unsigned short* W3 = Wt + 3 * 16384;
    unsigned short* W4 = Wt + 4 * 16384;
    unsigned short* W5 = Wt + 5 * 16384;
    unsigned short* W6 = Wt + 6 * 16384;
    unsigned short* W7 = Wt + 7 * 16384;
    unsigned short* W8 = Wt + 8 * 16384;
    unsigned short* W9 = Wt + 9 * 16384;

    f2bf_vec_k<<<(NKW * 32 + 255) / 256, 256, 0, stream>>>(x_kw, xkw_bf, NKW * 32);
    f2bf_vec_k<<<(NRT * 32 + 255) / 256, 256, 0, stream>>>(x_rt, xrt_bf, NRT * 32);

    // ---- bucket build + d-major sort per relation ----
    auto build = [&](const int* src, const int* dst, int E, int nb, int* boff,
                     unsigned* pairs, unsigned* sp, int* goff, float* invd, int Ndst) {
        zero_k<<<(nb + 255) / 256, 256, 0, stream>>>(bcnt, nb);
        bhist_k<<<256, 256, 0, stream>>>(dst, E, bcnt, nb);
        bscan_k<<<1, 1024, 0, stream>>>(bcnt, nb, boff, bcur);
        bscatter_k<<<(E + 8191) / 8192, 256, 0, stream>>>(src, dst, E, boff, bcur, pairs, nb);
        sortb_k<<<nb, 256, 0, stream>>>(pairs, boff, sp, goff, invd, Ndst, E);
    };
    build(src_a, dst_a, EA, nb_kw, boff_a, pairs_a, sp_a, goff_a, invd_a, NKW);
    build(src_b, dst_b, EB, nb_kw, boff_b, pairs_b, sp_b, goff_b, invd_b, NKW);
    build(src_c, dst_c, EC, nb_rt, boff_c, pairs_c, sp_c, goff_c, invd_c, NRT);

    // ---- layer 1 ----
    gemm_dual_k<<<(NKW + 63) / 64, 256, 0, stream>>>(xkw_bf, NKW, W0, bc1, out_kw, W2, Yb);
    gemm_dual_k<<<(NRT + 63) / 64, 256, 0, stream>>>(xrt_bf, NRT, W4, bl1c, out_rt, W1, Ya);
    gemm_single_k<<<(NRT + 63) / 64, 256, 0, stream>>>(xrt_bf, NRT, W3, Yc);
    bagg_k<2, 1, 1><<<nb_kw, 512, 0, stream>>>(out_kw, NKW,
                                               sp_a, goff_a, invd_a, Ya,
                                               sp_b, goff_b, invd_b, Yb,
                                               nullptr, kw1_bf);
    bagg_k<1, 1, 1><<<nb_rt, 512, 0, stream>>>(out_rt, NRT,
                                               sp_c, goff_c, invd_c, Yc,
                                               nullptr, nullptr, nullptr, nullptr,
                                               nullptr, rt1_bf);

    // ---- layer 2 ----
    gemm_dual_k<<<(NKW + 63) / 64, 256, 0, stream>>>(kw1_bf, NKW, W5, bc2, out_kw, W7, Yb);
    gemm_dual_k<<<(NRT + 63) / 64, 256, 0, stream>>>(rt1_bf, NRT, W9, bl2c, out_rt, W6, Ya);
    gemm_single_k<<<(NRT + 63) / 64, 256, 0, stream>>>(rt1_bf, NRT, W8, Yc);
    bagg_k<2, 0, 0><<<nb_kw, 512, 0, stream>>>(out_kw, NKW,
                                               sp_a, goff_a, invd_a, Ya,
                                               sp_b, goff_b, invd_b, Yb,
                                               out_kw, nullptr);
    bagg_k<1, 0, 0><<<nb_rt, 512, 0, stream>>>(out_rt, NRT,
                                               sp_c, goff_c, invd_c, Yc,
                                               nullptr, nullptr, nullptr, nullptr,
                                               out_rt, nullptr);
}

// Round 6
// 688.652 us; speedup vs baseline: 8.4497x; 1.0413x over previous
//
#include <hip/hip_runtime.h>

typedef __attribute__((ext_vector_type(8))) short bf16x8;
typedef __attribute__((ext_vector_type(4))) float f32x4;

static __device__ __forceinline__ unsigned short f2bf(float f) {
    unsigned int u = __float_as_uint(f);
    u += 0x7fffu + ((u >> 16) & 1u);   // round-to-nearest-even
    return (unsigned short)(u >> 16);
}
static __device__ __forceinline__ float bf2f(unsigned short h) {
    return __uint_as_float(((unsigned int)h) << 16);
}

#define BSH 6
#define BUCKET 64
#define NBMAX 1600
#define CHSH 13   // source chunk = src >> 13; clamped to 15

// ---------------- prep ----------------

struct PrepArgs {
    const float* W[10];
    const float* Wa[10];
    const float* b1a; const float* b1b; const float* b2a; const float* b2b;
};

__global__ void prep_k(PrepArgs pa, unsigned short* __restrict__ Wt,
                       float* __restrict__ bc1, float* __restrict__ bc2) {
    int blk = blockIdx.x;
    if (blk < 640) {
        int slot = blk >> 6;
        int i = ((blk & 63) << 8) + threadIdx.x;
        float v = pa.W[slot][i];
        const float* w2 = pa.Wa[slot];
        if (w2) v += w2[i];
        int k = i >> 7, n = i & 127;
        Wt[slot * 16384 + n * 128 + k] = f2bf(v);
    } else {
        int t = threadIdx.x;
        if (t < 128) bc1[t] = pa.b1a[t] + pa.b1b[t];
        else bc2[t - 128] = pa.b2a[t - 128] + pa.b2b[t - 128];
    }
}

// convert both x arrays in one kernel
__global__ void f2bf2_k(const float* __restrict__ xa, unsigned short* __restrict__ ya, int n4a,
                        const float* __restrict__ xb, unsigned short* __restrict__ yb, int n4b) {
    int i = blockIdx.x * 256 + threadIdx.x;
    const float* x; unsigned short* y; int idx;
    if (i < n4a) { x = xa; y = ya; idx = i; }
    else if (i < n4a + n4b) { x = xb; y = yb; idx = i - n4a; }
    else return;
    float4 v = ((const float4*)x)[idx];
    ushort4 o;
    o.x = f2bf(v.x); o.y = f2bf(v.y); o.z = f2bf(v.z); o.w = f2bf(v.w);
    ((ushort4*)y)[idx] = o;
}

// ---------------- fused bucket build ----------------

struct Rel {
    const int* src; const int* dst; int E; int nb; int Ndst;
    int hblk0, hnblk;          // bhist block range
    int sblk0, snblk;          // bscatter block range
    int oblk0;                 // sortb block offset
    int* bcnt; int* boff; int* bcur;
    unsigned* pairs; unsigned* ssrc; int* goff; float* invd;
};
struct Rels { Rel r[3]; };

__global__ void bhist3_k(Rels R) {
    const Rel* r;
    int bid = blockIdx.x;
    if (bid < R.r[1].hblk0) r = &R.r[0];
    else if (bid < R.r[2].hblk0) r = &R.r[1];
    else r = &R.r[2];
    __shared__ int h[NBMAX];
    for (int i = threadIdx.x; i < r->nb; i += 256) h[i] = 0;
    __syncthreads();
    for (int e = (bid - r->hblk0) * 256 + threadIdx.x; e < r->E; e += r->hnblk * 256)
        atomicAdd(&h[r->dst[e] >> BSH], 1);
    __syncthreads();
    for (int i = threadIdx.x; i < r->nb; i += 256)
        if (h[i]) atomicAdd(&r->bcnt[i], h[i]);
}

// 3 blocks, 1024 threads: block b scans relation b (nb <= 2048)
__global__ void bscan3_k(Rels R) {
    const Rel* r = &R.r[blockIdx.x];
    __shared__ int s[1024];
    int t = threadIdx.x;
    int nb = r->nb;
    int e0 = 2 * t, e1 = 2 * t + 1;
    int v0 = (e0 < nb) ? r->bcnt[e0] : 0;
    int v1 = (e1 < nb) ? r->bcnt[e1] : 0;
    s[t] = v0 + v1;
    __syncthreads();
    for (int o = 1; o < 1024; o <<= 1) {
        int x = (t >= o) ? s[t - o] : 0;
        __syncthreads();
        s[t] += x;
        __syncthreads();
    }
    int P = s[t] - (v0 + v1);
    if (e0 <= nb) { r->boff[e0] = P; if (e0 < nb) r->bcur[e0] = 0; }
    if (e1 <= nb) { r->boff[e1] = P + v0; if (e1 < nb) r->bcur[e1] = 0; }
}

__global__ __launch_bounds__(256) void bscatter3_k(Rels R) {
    const Rel* r;
    int bid = blockIdx.x;
    if (bid < R.r[1].sblk0) r = &R.r[0];
    else if (bid < R.r[2].sblk0) r = &R.r[1];
    else r = &R.r[2];
    __shared__ int h[NBMAX];
    __shared__ int base[NBMAX];
    int t = threadIdx.x;
    int nb = r->nb, E = r->E;
    for (int i = t; i < nb; i += 256) h[i] = 0;
    __syncthreads();
    int e0 = (bid - r->sblk0) * 8192;
    for (int i = 0; i < 32; i++) {
        int e = e0 + i * 256 + t;
        if (e < E) atomicAdd(&h[r->dst[e] >> BSH], 1);
    }
    __syncthreads();
    for (int i = t; i < nb; i += 256) {
        int c = h[i];
        base[i] = c ? (r->boff[i] + atomicAdd(&r->bcur[i], c)) : 0;
    }
    __syncthreads();
    for (int i = t; i < nb; i += 256) h[i] = 0;
    __syncthreads();
    for (int i = 0; i < 32; i++) {
        int e = e0 + i * 256 + t;
        if (e < E) {
            int d = r->dst[e];
            int b = d >> BSH;
            int pos = base[b] + atomicAdd(&h[b], 1);
            r->pairs[pos] = ((unsigned)(d & (BUCKET - 1)) << 17) | (unsigned)r->src[e];
        }
    }
}

// per-bucket counting sort; bin = ((d&7)<<7) | ((d>>3)<<4) | ch.
// sub-run (16 bins) = one (wave, row) pair. goff slot = (d&7)*8 + (d>>3).
__global__ __launch_bounds__(256) void sortb3_k(Rels R) {
    const Rel* r;
    int bid = blockIdx.x;
    if (bid < R.r[1].oblk0) r = &R.r[0];
    else if (bid < R.r[2].oblk0) r = &R.r[1];
    else r = &R.r[2];
    int b = bid - r->oblk0;
    __shared__ int cnt[1024];
    __shared__ int sc[256];
    int t = threadIdx.x;
    for (int i = t; i < 1024; i += 256) cnt[i] = 0;
    __syncthreads();
    int j0 = r->boff[b], j1 = r->boff[b + 1];
    for (int j = j0 + t; j < j1; j += 256) {
        unsigned p = r->pairs[j];
        int d = (p >> 17) & 63;
        int ch = (int)((p & 0x1ffffu) >> CHSH); if (ch > 15) ch = 15;
        int bin = ((d & 7) << 7) | ((d >> 3) << 4) | ch;
        atomicAdd(&cnt[bin], 1);
    }
    __syncthreads();
    if (t < 64) {
        int b0 = ((t & 7) << 7) | ((t >> 3) << 4);
        int c = 0;
#pragma unroll
        for (int i = 0; i < 16; i++) c += cnt[b0 + i];
        int dd = (b << BSH) + t;
        if (dd < r->Ndst) r->invd[dd] = 1.f / (float)(c > 0 ? c : 1);
    }
    int c0 = cnt[4 * t], c1 = cnt[4 * t + 1], c2 = cnt[4 * t + 2], c3 = cnt[4 * t + 3];
    int tot = c0 + c1 + c2 + c3;
    sc[t] = tot;
    __syncthreads();
    for (int o = 1; o < 256; o <<= 1) {
        int x = (t >= o) ? sc[t - o] : 0;
        __syncthreads();
        sc[t] += x;
        __syncthreads();
    }
    int base = j0 + sc[t] - tot;
    if ((t & 3) == 0) r->goff[b * 64 + (t >> 2)] = base;
    cnt[4 * t] = base;
    cnt[4 * t + 1] = base + c0;
    cnt[4 * t + 2] = base + c0 + c1;
    cnt[4 * t + 3] = base + c0 + c1 + c2;
    if (t == 0 && b == (R.r == nullptr ? 0 : 0) + (r->nb - 1)) r->goff[r->nb * 64] = r->E;
    __syncthreads();
    for (int j = j0 + t; j < j1; j += 256) {
        unsigned p = r->pairs[j];
        int d = (p >> 17) & 63;
        int ch = (int)((p & 0x1ffffu) >> CHSH); if (ch > 15) ch = 15;
        int bin = ((d & 7) << 7) | ((d >> 3) << 4) | ch;
        int pos = atomicAdd(&cnt[bin], 1);
        r->ssrc[pos] = p & 0x1ffffu;
    }
}

// ---------------- MFMA GEMMs ----------------
// A-frag: lane l holds A[row0 + (l&15)][kc*32 + (l>>4)*8 + 0..7]
// C/D: lane l, reg j -> row (l>>4)*4 + j, col l&15   [m89]

__global__ __launch_bounds__(256) void gemm_single_k(const unsigned short* __restrict__ A, int N,
                                                     const unsigned short* __restrict__ Wt,
                                                     unsigned short* __restrict__ Cb) {
    int wv = threadIdx.x >> 6, lane = threadIdx.x & 63;
    int r16 = lane & 15, g = lane >> 4;
    int row0 = blockIdx.x * 64 + wv * 16;
    int arow = row0 + r16;
    int arow_c = arow < N ? arow : N - 1;
    const bf16x8* Arow = (const bf16x8*)(A + (size_t)arow_c * 128);
    bf16x8 af[4];
#pragma unroll
    for (int kc = 0; kc < 4; kc++) af[kc] = Arow[kc * 4 + g];
    f32x4 acc[8];
#pragma unroll
    for (int ct = 0; ct < 8; ct++) { f32x4 z = {0.f, 0.f, 0.f, 0.f}; acc[ct] = z; }
#pragma unroll
    for (int kc = 0; kc < 4; kc++) {
#pragma unroll
        for (int ct = 0; ct < 8; ct++) {
            bf16x8 bfrag = *(const bf16x8*)(Wt + ((ct * 16 + r16) << 7) + kc * 32 + g * 8);
            acc[ct] = __builtin_amdgcn_mfma_f32_16x16x32_bf16(af[kc], bfrag, acc[ct], 0, 0, 0);
        }
    }
#pragma unroll
    for (int ct = 0; ct < 8; ct++) {
        int col = ct * 16 + r16;
#pragma unroll
        for (int j = 0; j < 4; j++) {
            int r = row0 + g * 4 + j;
            if (r < N) Cb[(size_t)r * 128 + col] = f2bf(acc[ct][j]);
        }
    }
}

// Z = A@W1 + bias1 (bf16), C2 = A@W2 (bf16); shared A-fragments
__global__ __launch_bounds__(256) void gemm_dual_k(const unsigned short* __restrict__ A, int N,
                                                   const unsigned short* __restrict__ Wt1,
                                                   const float* __restrict__ bias1,
                                                   unsigned short* __restrict__ Z1,
                                                   const unsigned short* __restrict__ Wt2,
                                                   unsigned short* __restrict__ C2) {
    int wv = threadIdx.x >> 6, lane = threadIdx.x & 63;
    int r16 = lane & 15, g = lane >> 4;
    int row0 = blockIdx.x * 64 + wv * 16;
    int arow = row0 + r16;
    int arow_c = arow < N ? arow : N - 1;
    const bf16x8* Arow = (const bf16x8*)(A + (size_t)arow_c * 128);
    bf16x8 af[4];
#pragma unroll
    for (int kc = 0; kc < 4; kc++) af[kc] = Arow[kc * 4 + g];
    f32x4 acc1[8], acc2[8];
#pragma unroll
    for (int ct = 0; ct < 8; ct++) {
        f32x4 z = {0.f, 0.f, 0.f, 0.f};
        acc1[ct] = z; acc2[ct] = z;
    }
#pragma unroll
    for (int kc = 0; kc < 4; kc++) {
#pragma unroll
        for (int ct = 0; ct < 8; ct++) {
            int wo = ((ct * 16 + r16) << 7) + kc * 32 + g * 8;
            bf16x8 b1 = *(const bf16x8*)(Wt1 + wo);
            acc1[ct] = __builtin_amdgcn_mfma_f32_16x16x32_bf16(af[kc], b1, acc1[ct], 0, 0, 0);
            bf16x8 b2 = *(const bf16x8*)(Wt2 + wo);
            acc2[ct] = __builtin_amdgcn_mfma_f32_16x16x32_bf16(af[kc], b2, acc2[ct], 0, 0, 0);
        }
    }
#pragma unroll
    for (int ct = 0; ct < 8; ct++) {
        int col = ct * 16 + r16;
        float b = bias1[col];
#pragma unroll
        for (int j = 0; j < 4; j++) {
            int r = row0 + g * 4 + j;
            if (r < N) {
                Z1[(size_t)r * 128 + col] = f2bf(acc1[ct][j] + b);
                C2[(size_t)r * 128 + col] = f2bf(acc2[ct][j]);
            }
        }
    }
}

// ---------------- bucket aggregation: full wave per dst row ----------------
// Block = one 64-dst bucket, 512 threads = 8 waves. Wave w owns rows d = r*8+w,
// r in 0..7; run [goff[b*64+w*8+r], next). Lanes: half h=lane>>5 takes edges
// j+2k+h (16 edges in flight), q=lane&31 covers features 4q..4q+3. Cross-half
// combine via shfl_xor(32); both halves flush disjoint e-slots. No divergence,
// no float atomics.
template <int NREL, int RELU, int OUTBF16>
__global__ __launch_bounds__(512) void bagg_k(const unsigned short* __restrict__ Zin, int Ndst,
                                              const unsigned* __restrict__ sp0,
                                              const int* __restrict__ goff0,
                                              const float* __restrict__ invd0,
                                              const unsigned short* __restrict__ Y0,
                                              const unsigned* __restrict__ sp1,
                                              const int* __restrict__ goff1,
                                              const float* __restrict__ invd1,
                                              const unsigned short* __restrict__ Y1,
                                              float* __restrict__ OutF,
                                              unsigned short* __restrict__ OutB) {
    __shared__ float acc[BUCKET * 128];
    int t = threadIdx.x;
    int b = blockIdx.x;
    int dst0 = b << BSH;
    int nrow = Ndst - dst0; if (nrow > BUCKET) nrow = BUCKET;

    // init acc from Zin bf16 (swizzled: feature 4m+e at r*128 + e*32 + m)
    for (int c = t; c < BUCKET * 32; c += 512) {
        int r = c >> 5, m = c & 31;
        float z0 = 0.f, z1 = 0.f, z2 = 0.f, z3 = 0.f;
        if (r < nrow) {
            ushort4 z = *(const ushort4*)(Zin + (size_t)(dst0 + r) * 128 + (m << 2));
            z0 = bf2f(z.x); z1 = bf2f(z.y); z2 = bf2f(z.z); z3 = bf2f(z.w);
        }
        acc[r * 128 + m] = z0;
        acc[r * 128 + 32 + m] = z1;
        acc[r * 128 + 64 + m] = z2;
        acc[r * 128 + 96 + m] = z3;
    }
    __syncthreads();

    int w = t >> 6, lane = t & 63;
    int h = lane >> 5, q = lane & 31;
    int e0 = h * 2;   // this half's flush slots: e0, e0+1
#pragma unroll 1
    for (int rel = 0; rel < NREL; rel++) {
        const unsigned* sp = rel ? sp1 : sp0;
        const int* goff = rel ? goff1 : goff0;
        const float* invd = rel ? invd1 : invd0;
        const unsigned short* Y = rel ? Y1 : Y0;
#pragma unroll 1
        for (int r = 0; r < 8; r++) {
            int g = b * 64 + w * 8 + r;
            int jg0 = goff[g], jg1 = goff[g + 1];
            if (jg0 >= jg1) continue;
            int d = (r << 3) | w;
            float a0 = 0.f, a1 = 0.f, a2 = 0.f, a3 = 0.f;
#pragma unroll 1
            for (int j = jg0; j < jg1; j += 16) {
                ushort4 v[8];
#pragma unroll
                for (int k = 0; k < 8; k++) {
                    int jj = j + 2 * k + h;
                    jj = jj < jg1 ? jj : jg1 - 1;
                    int s = (int)sp[jj];
                    v[k] = *(const ushort4*)(Y + ((size_t)s << 7) + (q << 2));
                }
#pragma unroll
                for (int k = 0; k < 8; k++) {
                    if (j + 2 * k + h < jg1) {
                        a0 += bf2f(v[k].x);
                        a1 += bf2f(v[k].y);
                        a2 += bf2f(v[k].z);
                        a3 += bf2f(v[k].w);
                    }
                }
            }
            // combine halves (each lane ends with the full-row sums)
            a0 += __shfl_xor(a0, 32);
            a1 += __shfl_xor(a1, 32);
            a2 += __shfl_xor(a2, 32);
            a3 += __shfl_xor(a3, 32);
            float inv = invd[dst0 + d];
            int ba = d * 128 + q;
            // halves flush disjoint feature slots (2-way bank alias = free)
            if (h == 0) {
                acc[ba] += a0 * inv;
                acc[ba + 32] += a1 * inv;
            } else {
                acc[ba + 64] += a2 * inv;
                acc[ba + 96] += a3 * inv;
            }
        }
    }
    __syncthreads();
    // finalize
    for (int c = t; c < BUCKET * 32; c += 512) {
        int r = c >> 5, m = c & 31;
        if (r < nrow) {
            float x0 = acc[r * 128 + m];
            float x1 = acc[r * 128 + 32 + m];
            float x2 = acc[r * 128 + 64 + m];
            float x3 = acc[r * 128 + 96 + m];
            if (RELU) {
                x0 = fmaxf(x0, 0.f); x1 = fmaxf(x1, 0.f);
                x2 = fmaxf(x2, 0.f); x3 = fmaxf(x3, 0.f);
            }
            size_t o = (size_t)(dst0 + r) * 128 + (m << 2);
            if (OUTBF16) {
                ushort4 ov;
                ov.x = f2bf(x0); ov.y = f2bf(x1); ov.z = f2bf(x2); ov.w = f2bf(x3);
                *(ushort4*)(OutB + o) = ov;
            } else {
                *(float4*)(OutF + o) = make_float4(x0, x1, x2, x3);
            }
        }
    }
}

// ---------------- launch ----------------

static inline size_t align256(size_t x) { return (x + 255) & ~size_t(255); }

extern "C" void kernel_launch(void* const* d_in, const int* in_sizes, int n_in,
                              void* d_out, int out_size, void* d_ws, size_t ws_size,
                              hipStream_t stream) {
    const float* x_kw = (const float*)d_in[0];
    const float* x_rt = (const float*)d_in[1];
    const int* src_a = (const int*)d_in[2];
    const int* dst_a = (const int*)d_in[3];
    const int* src_b = (const int*)d_in[4];
    const int* dst_b = (const int*)d_in[5];
    const int* src_c = (const int*)d_in[6];
    const int* dst_c = (const int*)d_in[7];
    const float *Wl1a = (const float*)d_in[8],  *bl1a = (const float*)d_in[9],  *Wr1a = (const float*)d_in[10];
    const float *Wl1b = (const float*)d_in[11], *bl1b = (const float*)d_in[12], *Wr1b = (const float*)d_in[13];
    const float *Wl1c = (const float*)d_in[14], *bl1c = (const float*)d_in[15], *Wr1c = (const float*)d_in[16];
    const float *Wl2a = (const float*)d_in[17], *bl2a = (const float*)d_in[18], *Wr2a = (const float*)d_in[19];
    const float *Wl2b = (const float*)d_in[20], *bl2b = (const float*)d_in[21], *Wr2b = (const float*)d_in[22];
    const float *Wl2c = (const float*)d_in[23], *bl2c = (const float*)d_in[24], *Wr2c = (const float*)d_in[25];

    const int NKW = in_sizes[0] / 128;
    const int NRT = in_sizes[1] / 128;
    const int EA = in_sizes[2], EB = in_sizes[4], EC = in_sizes[6];
    const int nb_kw = (NKW + BUCKET - 1) / BUCKET;
    const int nb_rt = (NRT + BUCKET - 1) / BUCKET;

    char* ws = (char*)d_ws;
    size_t off = 0;
    auto alloc = [&](size_t bytes) -> char* {
        off = align256(off);
        char* p = ws + off;
        off += bytes;
        return p;
    };
    unsigned short* Wt = (unsigned short*)alloc(10 * 16384 * 2);
    float* bc1 = (float*)alloc(128 * 4);
    float* bc2 = (float*)alloc(128 * 4);
    int* bcnt3 = (int*)alloc(3 * NBMAX * 4);
    int* bcur3 = (int*)alloc(3 * NBMAX * 4);
    int* boff_a = (int*)alloc((NBMAX + 1) * 4);
    int* boff_b = (int*)alloc((NBMAX + 1) * 4);
    int* boff_c = (int*)alloc((NBMAX + 1) * 4);
    int* goff_a = (int*)alloc(((size_t)nb_kw * 64 + 1) * 4);
    int* goff_b = (int*)alloc(((size_t)nb_kw * 64 + 1) * 4);
    int* goff_c = (int*)alloc(((size_t)nb_rt * 64 + 1) * 4);
    float* invd_a = (float*)alloc((size_t)NKW * 4);
    float* invd_b = (float*)alloc((size_t)NKW * 4);
    float* invd_c = (float*)alloc((size_t)NRT * 4);
    unsigned* pairs_a = (unsigned*)alloc((size_t)EA * 4);
    unsigned* pairs_b = (unsigned*)alloc((size_t)EB * 4);
    unsigned* pairs_c = (unsigned*)alloc((size_t)EC * 4);
    unsigned* sp_a = (unsigned*)alloc((size_t)EA * 4);
    unsigned* sp_b = (unsigned*)alloc((size_t)EB * 4);
    unsigned* sp_c = (unsigned*)alloc((size_t)EC * 4);
    unsigned short* xkw_bf = (unsigned short*)alloc((size_t)NKW * 128 * 2);
    unsigned short* xrt_bf = (unsigned short*)alloc((size_t)NRT * 128 * 2);
    unsigned short* Yb = (unsigned short*)alloc((size_t)NKW * 128 * 2);
    unsigned short* Zkw = (unsigned short*)alloc((size_t)NKW * 128 * 2);
    unsigned short* Zrt = (unsigned short*)alloc((size_t)NRT * 128 * 2);
    (void)ws_size;
    unsigned short* Ya = (unsigned short*)pairs_b;   // pairs dead after sort
    unsigned short* Yc = (unsigned short*)pairs_a;
    unsigned short* kw1_bf = xkw_bf;                 // x bf16 dead after L1 GEMMs
    unsigned short* rt1_bf = xrt_bf;

    float* out_kw = (float*)d_out;
    float* out_rt = out_kw + (size_t)NKW * 128;

    // ---- prep ----
    PrepArgs pa;
    pa.W[0] = Wr1a; pa.Wa[0] = Wr1b;
    pa.W[1] = Wl1a; pa.Wa[1] = nullptr;
    pa.W[2] = Wl1b; pa.Wa[2] = nullptr;
    pa.W[3] = Wl1c; pa.Wa[3] = nullptr;
    pa.W[4] = Wr1c; pa.Wa[4] = nullptr;
    pa.W[5] = Wr2a; pa.Wa[5] = Wr2b;
    pa.W[6] = Wl2a; pa.Wa[6] = nullptr;
    pa.W[7] = Wl2b; pa.Wa[7] = nullptr;
    pa.W[8] = Wl2c; pa.Wa[8] = nullptr;
    pa.W[9] = Wr2c; pa.Wa[9] = nullptr;
    pa.b1a = bl1a; pa.b1b = bl1b; pa.b2a = bl2a; pa.b2b = bl2b;
    prep_k<<<641, 256, 0, stream>>>(pa, Wt, bc1, bc2);
    unsigned short* W0 = Wt + 0 * 16384;
    unsigned short* W1 = Wt + 1 * 16384;
    unsigned short* W2 = Wt + 2 * 16384;
    unsigned short* W3 = Wt + 3 * 16384;
    unsigned short* W4 = Wt + 4 * 16384;
    unsigned short* W5 = Wt + 5 * 16384;
    unsigned short* W6 = Wt + 6 * 16384;
    unsigned short* W7 = Wt + 7 * 16384;
    unsigned short* W8 = Wt + 8 * 16384;
    unsigned short* W9 = Wt + 9 * 16384;

    f2bf2_k<<<(NKW * 32 + NRT * 32 + 255) / 256, 256, 0, stream>>>(
        x_kw, xkw_bf, NKW * 32, x_rt, xrt_bf, NRT * 32);

    // ---- fused bucket build ----
    hipMemsetAsync(bcnt3, 0, 3 * NBMAX * 4, stream);
    Rels R;
    int hA = 128, hB = 128, hC = 64;
    int sA = (EA + 8191) / 8192, sB = (EB + 8191) / 8192, sC = (EC + 8191) / 8192;
    R.r[0] = {src_a, dst_a, EA, nb_kw, NKW, 0, hA, 0, sA, 0,
              bcnt3, boff_a, bcur3, pairs_a, sp_a, goff_a, invd_a};
    R.r[1] = {src_b, dst_b, EB, nb_kw, NKW, hA, hB, sA, sB, nb_kw,
              bcnt3 + NBMAX, boff_b, bcur3 + NBMAX, pairs_b, sp_b, goff_b, invd_b};
    R.r[2] = {src_c, dst_c, EC, nb_rt, NRT, hA + hB, hC, sA + sB, sC, 2 * nb_kw,
              bcnt3 + 2 * NBMAX, boff_c, bcur3 + 2 * NBMAX, pairs_c, sp_c, goff_c, invd_c};
    bhist3_k<<<hA + hB + hC, 256, 0, stream>>>(R);
    bscan3_k<<<3, 1024, 0, stream>>>(R);
    bscatter3_k<<<sA + sB + sC, 256, 0, stream>>>(R);
    sortb3_k<<<2 * nb_kw + nb_rt, 256, 0, stream>>>(R);

    // ---- layer 1 ----
    gemm_dual_k<<<(NKW + 63) / 64, 256, 0, stream>>>(xkw_bf, NKW, W0, bc1, Zkw, W2, Yb);
    gemm_dual_k<<<(NRT + 63) / 64, 256, 0, stream>>>(xrt_bf, NRT, W4, bl1c, Zrt, W1, Ya);
    gemm_single_k<<<(NRT + 63) / 64, 256, 0, stream>>>(xrt_bf, NRT, W3, Yc);
    bagg_k<2, 1, 1><<<nb_kw, 512, 0, stream>>>(Zkw, NKW,
                                               sp_a, goff_a, invd_a, Ya,
                                               sp_b, goff_b, invd_b, Yb,
                                               nullptr, kw1_bf);
    bagg_k<1, 1, 1><<<nb_rt, 512, 0, stream>>>(Zrt, NRT,
                                               sp_c, goff_c, invd_c, Yc,
                                               nullptr, nullptr, nullptr, nullptr,
                                               nullptr, rt1_bf);

    // ---- layer 2 ----
    gemm_dual_k<<<(NKW + 63) / 64, 256, 0, stream>>>(kw1_bf, NKW, W5, bc2, Zkw, W7, Yb);
    gemm_dual_k<<<(NRT + 63) / 64, 256, 0, stream>>>(rt1_bf, NRT, W9, bl2c, Zrt, W6, Ya);
    gemm_single_k<<<(NRT + 63) / 64, 256, 0, stream>>>(rt1_bf, NRT, W8, Yc);
    bagg_k<2, 0, 0><<<nb_kw, 512, 0, stream>>>(Zkw, NKW,
                                               sp_a, goff_a, invd_a, Ya,
                                               sp_b, goff_b, invd_b, Yb,
                                               out_kw, nullptr);
    bagg_k<1, 0, 0><<<nb_rt, 512, 0, stream>>>(Zrt, NRT,
                                               sp_c, goff_c, invd_c, Yc,
                                               nullptr, nullptr, nullptr, nullptr,
                                               out_rt, nullptr);
}

// Round 7
// 580.328 us; speedup vs baseline: 10.0269x; 1.1867x over previous
//
#include <hip/hip_runtime.h>

typedef __attribute__((ext_vector_type(8))) short bf16x8;
typedef __attribute__((ext_vector_type(4))) float f32x4;
typedef __attribute__((ext_vector_type(2))) float f32x2;

static __device__ __forceinline__ unsigned short f2bf(float f) {
    unsigned int u = __float_as_uint(f);
    u += 0x7fffu + ((u >> 16) & 1u);   // round-to-nearest-even
    return (unsigned short)(u >> 16);
}
static __device__ __forceinline__ float bf2f(unsigned short h) {
    return __uint_as_float(((unsigned int)h) << 16);
}

#define BSH 6
#define BUCKET 64
#define NBMAX 1600
#define CHSH 13

// ---------------- prep ----------------

struct PrepArgs {
    const float* W[10];
    const float* Wa[10];
    const float* b1a; const float* b1b; const float* b2a; const float* b2b;
};

__global__ void prep_k(PrepArgs pa, unsigned short* __restrict__ Wt,
                       float* __restrict__ bc1, float* __restrict__ bc2) {
    int blk = blockIdx.x;
    if (blk < 640) {
        int slot = blk >> 6;
        int i = ((blk & 63) << 8) + threadIdx.x;
        float v = pa.W[slot][i];
        const float* w2 = pa.Wa[slot];
        if (w2) v += w2[i];
        int k = i >> 7, n = i & 127;
        Wt[slot * 16384 + n * 128 + k] = f2bf(v);
    } else {
        int t = threadIdx.x;
        if (t < 128) bc1[t] = pa.b1a[t] + pa.b1b[t];
        else bc2[t - 128] = pa.b2a[t - 128] + pa.b2b[t - 128];
    }
}

// ---------------- fused bucket build ----------------

struct Rel {
    const int* src; const int* dst; int E; int nb; int Ndst;
    int hblk0, hnblk;
    int sblk0, snblk;
    int oblk0;
    int* bcnt; int* boff; int* bcur;
    unsigned* pairs; unsigned* ssrc; int* goff; float* invd;
};
struct Rels { Rel r[3]; };

__global__ void bhist3_k(Rels R) {
    const Rel* r;
    int bid = blockIdx.x;
    if (bid < R.r[1].hblk0) r = &R.r[0];
    else if (bid < R.r[2].hblk0) r = &R.r[1];
    else r = &R.r[2];
    __shared__ int h[NBMAX];
    for (int i = threadIdx.x; i < r->nb; i += 256) h[i] = 0;
    __syncthreads();
    for (int e = (bid - r->hblk0) * 256 + threadIdx.x; e < r->E; e += r->hnblk * 256)
        atomicAdd(&h[r->dst[e] >> BSH], 1);
    __syncthreads();
    for (int i = threadIdx.x; i < r->nb; i += 256)
        if (h[i]) atomicAdd(&r->bcnt[i], h[i]);
}

__global__ void bscan3_k(Rels R) {
    const Rel* r = &R.r[blockIdx.x];
    __shared__ int s[1024];
    int t = threadIdx.x;
    int nb = r->nb;
    int e0 = 2 * t, e1 = 2 * t + 1;
    int v0 = (e0 < nb) ? r->bcnt[e0] : 0;
    int v1 = (e1 < nb) ? r->bcnt[e1] : 0;
    s[t] = v0 + v1;
    __syncthreads();
    for (int o = 1; o < 1024; o <<= 1) {
        int x = (t >= o) ? s[t - o] : 0;
        __syncthreads();
        s[t] += x;
        __syncthreads();
    }
    int P = s[t] - (v0 + v1);
    if (e0 <= nb) { r->boff[e0] = P; if (e0 < nb) r->bcur[e0] = 0; }
    if (e1 <= nb) { r->boff[e1] = P + v0; if (e1 < nb) r->bcur[e1] = 0; }
}

__global__ __launch_bounds__(256) void bscatter3_k(Rels R) {
    const Rel* r;
    int bid = blockIdx.x;
    if (bid < R.r[1].sblk0) r = &R.r[0];
    else if (bid < R.r[2].sblk0) r = &R.r[1];
    else r = &R.r[2];
    __shared__ int h[NBMAX];
    __shared__ int base[NBMAX];
    int t = threadIdx.x;
    int nb = r->nb, E = r->E;
    for (int i = t; i < nb; i += 256) h[i] = 0;
    __syncthreads();
    int e0 = (bid - r->sblk0) * 8192;
    for (int i = 0; i < 32; i++) {
        int e = e0 + i * 256 + t;
        if (e < E) atomicAdd(&h[r->dst[e] >> BSH], 1);
    }
    __syncthreads();
    for (int i = t; i < nb; i += 256) {
        int c = h[i];
        base[i] = c ? (r->boff[i] + atomicAdd(&r->bcur[i], c)) : 0;
    }
    __syncthreads();
    for (int i = t; i < nb; i += 256) h[i] = 0;
    __syncthreads();
    for (int i = 0; i < 32; i++) {
        int e = e0 + i * 256 + t;
        if (e < E) {
            int d = r->dst[e];
            int b = d >> BSH;
            int pos = base[b] + atomicAdd(&h[b], 1);
            r->pairs[pos] = ((unsigned)(d & (BUCKET - 1)) << 17) | (unsigned)r->src[e];
        }
    }
}

// bin = ((d&7)<<7) | ((d>>3)<<4) | ch; run (16 bins) = (wave w=d&7, row r=d>>3).
__global__ __launch_bounds__(256) void sortb3_k(Rels R) {
    const Rel* r;
    int bid = blockIdx.x;
    if (bid < R.r[1].oblk0) r = &R.r[0];
    else if (bid < R.r[2].oblk0) r = &R.r[1];
    else r = &R.r[2];
    int b = bid - r->oblk0;
    __shared__ int cnt[1024];
    __shared__ int sc[256];
    int t = threadIdx.x;
    for (int i = t; i < 1024; i += 256) cnt[i] = 0;
    __syncthreads();
    int j0 = r->boff[b], j1 = r->boff[b + 1];
    for (int j = j0 + t; j < j1; j += 256) {
        unsigned p = r->pairs[j];
        int d = (p >> 17) & 63;
        int ch = (int)((p & 0x1ffffu) >> CHSH); if (ch > 15) ch = 15;
        int bin = ((d & 7) << 7) | ((d >> 3) << 4) | ch;
        atomicAdd(&cnt[bin], 1);
    }
    __syncthreads();
    if (t < 64) {
        int b0 = ((t & 7) << 7) | ((t >> 3) << 4);
        int c = 0;
#pragma unroll
        for (int i = 0; i < 16; i++) c += cnt[b0 + i];
        int dd = (b << BSH) + t;
        if (dd < r->Ndst) r->invd[dd] = 1.f / (float)(c > 0 ? c : 1);
    }
    int c0 = cnt[4 * t], c1 = cnt[4 * t + 1], c2 = cnt[4 * t + 2], c3 = cnt[4 * t + 3];
    int tot = c0 + c1 + c2 + c3;
    sc[t] = tot;
    __syncthreads();
    for (int o = 1; o < 256; o <<= 1) {
        int x = (t >= o) ? sc[t - o] : 0;
        __syncthreads();
        sc[t] += x;
        __syncthreads();
    }
    int base = j0 + sc[t] - tot;
    if ((t & 3) == 0) r->goff[b * 64 + (t >> 2)] = base;
    cnt[4 * t] = base;
    cnt[4 * t + 1] = base + c0;
    cnt[4 * t + 2] = base + c0 + c1;
    cnt[4 * t + 3] = base + c0 + c1 + c2;
    if (t == 0 && b == r->nb - 1) r->goff[r->nb * 64] = r->E;
    __syncthreads();
    for (int j = j0 + t; j < j1; j += 256) {
        unsigned p = r->pairs[j];
        int d = (p >> 17) & 63;
        int ch = (int)((p & 0x1ffffu) >> CHSH); if (ch > 15) ch = 15;
        int bin = ((d & 7) << 7) | ((d >> 3) << 4) | ch;
        int pos = atomicAdd(&cnt[bin], 1);
        r->ssrc[pos] = p & 0x1ffffu;
    }
}

// ---------------- combined MFMA GEMMs (one launch per layer) ----------------
// kw blocks: dual (Z = A@W1+b -> bf16, C2 = A@W2 -> bf16)
// rt blocks: triple (Z, C2, C3) sharing one A read.
// A-frag: lane l holds A[row0+(l&15)][kc*32+(l>>4)*8+0..7]; C/D: row (l>>4)*4+j, col l&15.

struct GemmJobs {
    const void* Akw; int Nkw;
    const unsigned short* Wk1; const float* bk; unsigned short* Zkw;
    const unsigned short* Wk2; unsigned short* Ckw;
    const void* Art; int Nrt;
    const unsigned short* Wr1; const float* br; unsigned short* Zrt;
    const unsigned short* Wr2; unsigned short* Crt2;
    const unsigned short* Wr3; unsigned short* Crt3;
    int kwBlocks;
};

template <int AF32>
__global__ __launch_bounds__(256) void gemm3_k(GemmJobs G) {
    int bid = blockIdx.x;
    bool iskw = bid < G.kwBlocks;
    const void* A = iskw ? G.Akw : G.Art;
    int N = iskw ? G.Nkw : G.Nrt;
    int lane = threadIdx.x & 63;
    int r16 = lane & 15, g = lane >> 4;
    int row0 = (iskw ? bid : bid - G.kwBlocks) * 64 + (threadIdx.x >> 6) * 16;
    int arow = row0 + r16;
    int arow_c = arow < N ? arow : N - 1;

    bf16x8 af[4];
    if (AF32) {
        const float* Af = (const float*)A + (size_t)arow_c * 128 + g * 8;
#pragma unroll
        for (int kc = 0; kc < 4; kc++) {
            float4 u0 = *(const float4*)(Af + kc * 32);
            float4 u1 = *(const float4*)(Af + kc * 32 + 4);
            bf16x8 r;
            r[0] = (short)f2bf(u0.x); r[1] = (short)f2bf(u0.y);
            r[2] = (short)f2bf(u0.z); r[3] = (short)f2bf(u0.w);
            r[4] = (short)f2bf(u1.x); r[5] = (short)f2bf(u1.y);
            r[6] = (short)f2bf(u1.z); r[7] = (short)f2bf(u1.w);
            af[kc] = r;
        }
    } else {
        const bf16x8* Ar = (const bf16x8*)((const unsigned short*)A + (size_t)arow_c * 128);
#pragma unroll
        for (int kc = 0; kc < 4; kc++) af[kc] = Ar[kc * 4 + g];
    }

    if (iskw) {
        f32x4 acc1[8], acc2[8];
#pragma unroll
        for (int ct = 0; ct < 8; ct++) { f32x4 z = {0.f,0.f,0.f,0.f}; acc1[ct] = z; acc2[ct] = z; }
#pragma unroll
        for (int kc = 0; kc < 4; kc++) {
#pragma unroll
            for (int ct = 0; ct < 8; ct++) {
                int wo = ((ct * 16 + r16) << 7) + kc * 32 + g * 8;
                bf16x8 b1 = *(const bf16x8*)(G.Wk1 + wo);
                acc1[ct] = __builtin_amdgcn_mfma_f32_16x16x32_bf16(af[kc], b1, acc1[ct], 0, 0, 0);
                bf16x8 b2 = *(const bf16x8*)(G.Wk2 + wo);
                acc2[ct] = __builtin_amdgcn_mfma_f32_16x16x32_bf16(af[kc], b2, acc2[ct], 0, 0, 0);
            }
        }
#pragma unroll
        for (int ct = 0; ct < 8; ct++) {
            int col = ct * 16 + r16;
            float bb = G.bk[col];
#pragma unroll
            for (int j = 0; j < 4; j++) {
                int r = row0 + g * 4 + j;
                if (r < N) {
                    G.Zkw[(size_t)r * 128 + col] = f2bf(acc1[ct][j] + bb);
                    G.Ckw[(size_t)r * 128 + col] = f2bf(acc2[ct][j]);
                }
            }
        }
    } else {
        f32x4 acc1[8], acc2[8], acc3[8];
#pragma unroll
        for (int ct = 0; ct < 8; ct++) {
            f32x4 z = {0.f,0.f,0.f,0.f}; acc1[ct] = z; acc2[ct] = z; acc3[ct] = z;
        }
#pragma unroll
        for (int kc = 0; kc < 4; kc++) {
#pragma unroll
            for (int ct = 0; ct < 8; ct++) {
                int wo = ((ct * 16 + r16) << 7) + kc * 32 + g * 8;
                bf16x8 b1 = *(const bf16x8*)(G.Wr1 + wo);
                acc1[ct] = __builtin_amdgcn_mfma_f32_16x16x32_bf16(af[kc], b1, acc1[ct], 0, 0, 0);
                bf16x8 b2 = *(const bf16x8*)(G.Wr2 + wo);
                acc2[ct] = __builtin_amdgcn_mfma_f32_16x16x32_bf16(af[kc], b2, acc2[ct], 0, 0, 0);
                bf16x8 b3 = *(const bf16x8*)(G.Wr3 + wo);
                acc3[ct] = __builtin_amdgcn_mfma_f32_16x16x32_bf16(af[kc], b3, acc3[ct], 0, 0, 0);
            }
        }
#pragma unroll
        for (int ct = 0; ct < 8; ct++) {
            int col = ct * 16 + r16;
            float bb = G.br[col];
#pragma unroll
            for (int j = 0; j < 4; j++) {
                int r = row0 + g * 4 + j;
                if (r < N) {
                    G.Zrt[(size_t)r * 128 + col] = f2bf(acc1[ct][j] + bb);
                    G.Crt2[(size_t)r * 128 + col] = f2bf(acc2[ct][j]);
                    G.Crt3[(size_t)r * 128 + col] = f2bf(acc3[ct][j]);
                }
            }
        }
    }
}

// ---------------- combined bucket aggregation (kw + rt in one grid) ----------------
// Block = one 64-dst bucket, 8 waves. Wave w owns rows d=(r<<3)|w. Halves process
// interleaved edges (16 in flight/wave); uint2 loads; packed f32x2 accumulate
// (lo = x<<16, hi = x&0xffff0000); shfl_xor(32) combine; non-atomic LDS flush.
struct AggJob {
    const unsigned short* Zin; int Ndst;
    const unsigned* sp0; const int* goff0; const float* invd0; const unsigned short* Y0;
    const unsigned* sp1; const int* goff1; const float* invd1; const unsigned short* Y1;
    int nrel;
    float* OutF; unsigned short* OutB;
};

template <int RELU, int OUTBF16>
__global__ __launch_bounds__(512) void bagg2_k(AggJob JK, AggJob JR, int kwBlocks) {
    __shared__ float acc[BUCKET * 128];
    bool iskw = blockIdx.x < kwBlocks;
    AggJob J = iskw ? JK : JR;
    int b = iskw ? blockIdx.x : blockIdx.x - kwBlocks;
    int t = threadIdx.x;
    int dst0 = b << BSH;
    int nrow = J.Ndst - dst0; if (nrow > BUCKET) nrow = BUCKET;

    // init from Zin bf16 (swizzled: feature 4m+e at r*128 + e*32 + m)
    for (int c = t; c < BUCKET * 32; c += 512) {
        int r = c >> 5, m = c & 31;
        float z0 = 0.f, z1 = 0.f, z2 = 0.f, z3 = 0.f;
        if (r < nrow) {
            ushort4 z = *(const ushort4*)(J.Zin + (size_t)(dst0 + r) * 128 + (m << 2));
            z0 = bf2f(z.x); z1 = bf2f(z.y); z2 = bf2f(z.z); z3 = bf2f(z.w);
        }
        acc[r * 128 + m] = z0;
        acc[r * 128 + 32 + m] = z1;
        acc[r * 128 + 64 + m] = z2;
        acc[r * 128 + 96 + m] = z3;
    }
    __syncthreads();

    int w = t >> 6, lane = t & 63;
    int h = lane >> 5, q = lane & 31;
#pragma unroll 1
    for (int rel = 0; rel < J.nrel; rel++) {
        const unsigned* sp = rel ? J.sp1 : J.sp0;
        const int* goff = rel ? J.goff1 : J.goff0;
        const float* invd = rel ? J.invd1 : J.invd0;
        const unsigned short* Y = rel ? J.Y1 : J.Y0;
#pragma unroll 1
        for (int r = 0; r < 8; r++) {
            int g = b * 64 + w * 8 + r;
            int jg0 = goff[g], jg1 = goff[g + 1];
            if (jg0 >= jg1) continue;
            int d = (r << 3) | w;
            f32x2 a01 = {0.f, 0.f}, a23 = {0.f, 0.f};
#pragma unroll 1
            for (int j = jg0; j < jg1; j += 16) {
                uint2 v[8];
#pragma unroll
                for (int k = 0; k < 8; k++) {
                    int e = j + 2 * k + h;
                    e = e < jg1 ? e : jg1 - 1;
                    int s = (int)sp[e];
                    v[k] = *(const uint2*)(Y + ((size_t)s << 7) + (q << 2));
                }
#pragma unroll
                for (int k = 0; k < 8; k++) {
                    bool ok = (j + 2 * k + h) < jg1;
                    unsigned vx = ok ? v[k].x : 0u;
                    unsigned vy = ok ? v[k].y : 0u;
                    f32x2 x01 = { __uint_as_float(vx << 16),
                                  __uint_as_float(vx & 0xffff0000u) };
                    f32x2 x23 = { __uint_as_float(vy << 16),
                                  __uint_as_float(vy & 0xffff0000u) };
                    a01 += x01;
                    a23 += x23;
                }
            }
            a01.x += __shfl_xor(a01.x, 32); a01.y += __shfl_xor(a01.y, 32);
            a23.x += __shfl_xor(a23.x, 32); a23.y += __shfl_xor(a23.y, 32);
            float inv = invd[dst0 + d];
            float v0 = (h ? a23.x : a01.x) * inv;
            float v1 = (h ? a23.y : a01.y) * inv;
            int ba = d * 128 + q + h * 64;
            acc[ba] += v0;
            acc[ba + 32] += v1;
        }
    }
    __syncthreads();
    for (int c = t; c < BUCKET * 32; c += 512) {
        int r = c >> 5, m = c & 31;
        if (r < nrow) {
            float x0 = acc[r * 128 + m];
            float x1 = acc[r * 128 + 32 + m];
            float x2 = acc[r * 128 + 64 + m];
            float x3 = acc[r * 128 + 96 + m];
            if (RELU) {
                x0 = fmaxf(x0, 0.f); x1 = fmaxf(x1, 0.f);
                x2 = fmaxf(x2, 0.f); x3 = fmaxf(x3, 0.f);
            }
            size_t o = (size_t)(dst0 + r) * 128 + (m << 2);
            if (OUTBF16) {
                ushort4 ov;
                ov.x = f2bf(x0); ov.y = f2bf(x1); ov.z = f2bf(x2); ov.w = f2bf(x3);
                *(ushort4*)(J.OutB + o) = ov;
            } else {
                *(float4*)(J.OutF + o) = make_float4(x0, x1, x2, x3);
            }
        }
    }
}

// ---------------- launch ----------------

static inline size_t align256(size_t x) { return (x + 255) & ~size_t(255); }

extern "C" void kernel_launch(void* const* d_in, const int* in_sizes, int n_in,
                              void* d_out, int out_size, void* d_ws, size_t ws_size,
                              hipStream_t stream) {
    const float* x_kw = (const float*)d_in[0];
    const float* x_rt = (const float*)d_in[1];
    const int* src_a = (const int*)d_in[2];
    const int* dst_a = (const int*)d_in[3];
    const int* src_b = (const int*)d_in[4];
    const int* dst_b = (const int*)d_in[5];
    const int* src_c = (const int*)d_in[6];
    const int* dst_c = (const int*)d_in[7];
    const float *Wl1a = (const float*)d_in[8],  *bl1a = (const float*)d_in[9],  *Wr1a = (const float*)d_in[10];
    const float *Wl1b = (const float*)d_in[11], *bl1b = (const float*)d_in[12], *Wr1b = (const float*)d_in[13];
    const float *Wl1c = (const float*)d_in[14], *bl1c = (const float*)d_in[15], *Wr1c = (const float*)d_in[16];
    const float *Wl2a = (const float*)d_in[17], *bl2a = (const float*)d_in[18], *Wr2a = (const float*)d_in[19];
    const float *Wl2b = (const float*)d_in[20], *bl2b = (const float*)d_in[21], *Wr2b = (const float*)d_in[22];
    const float *Wl2c = (const float*)d_in[23], *bl2c = (const float*)d_in[24], *Wr2c = (const float*)d_in[25];

    const int NKW = in_sizes[0] / 128;
    const int NRT = in_sizes[1] / 128;
    const int EA = in_sizes[2], EB = in_sizes[4], EC = in_sizes[6];
    const int nb_kw = (NKW + BUCKET - 1) / BUCKET;
    const int nb_rt = (NRT + BUCKET - 1) / BUCKET;

    char* ws = (char*)d_ws;
    size_t off = 0;
    auto alloc = [&](size_t bytes) -> char* {
        off = align256(off);
        char* p = ws + off;
        off += bytes;
        return p;
    };
    unsigned short* Wt = (unsigned short*)alloc(10 * 16384 * 2);
    float* bc1 = (float*)alloc(128 * 4);
    float* bc2 = (float*)alloc(128 * 4);
    int* bcnt3 = (int*)alloc(3 * NBMAX * 4);
    int* bcur3 = (int*)alloc(3 * NBMAX * 4);
    int* boff_a = (int*)alloc((NBMAX + 1) * 4);
    int* boff_b = (int*)alloc((NBMAX + 1) * 4);
    int* boff_c = (int*)alloc((NBMAX + 1) * 4);
    int* goff_a = (int*)alloc(((size_t)nb_kw * 64 + 1) * 4);
    int* goff_b = (int*)alloc(((size_t)nb_kw * 64 + 1) * 4);
    int* goff_c = (int*)alloc(((size_t)nb_rt * 64 + 1) * 4);
    float* invd_a = (float*)alloc((size_t)NKW * 4);
    float* invd_b = (float*)alloc((size_t)NKW * 4);
    float* invd_c = (float*)alloc((size_t)NRT * 4);
    unsigned* pairs_a = (unsigned*)alloc((size_t)EA * 4);
    unsigned* pairs_b = (unsigned*)alloc((size_t)EB * 4);
    unsigned* pairs_c = (unsigned*)alloc((size_t)EC * 4);
    unsigned* sp_a = (unsigned*)alloc((size_t)EA * 4);
    unsigned* sp_b = (unsigned*)alloc((size_t)EB * 4);
    unsigned* sp_c = (unsigned*)alloc((size_t)EC * 4);
    unsigned short* Yb = (unsigned short*)alloc((size_t)NKW * 128 * 2);
    unsigned short* Zkw = (unsigned short*)alloc((size_t)NKW * 128 * 2);
    unsigned short* Zrt = (unsigned short*)alloc((size_t)NRT * 128 * 2);
    unsigned short* kw1_bf = (unsigned short*)alloc((size_t)NKW * 128 * 2);
    unsigned short* rt1_bf = (unsigned short*)alloc((size_t)NRT * 128 * 2);
    (void)ws_size;
    unsigned short* Ya = (unsigned short*)pairs_b;   // pairs dead after sortb3
    unsigned short* Yc = (unsigned short*)pairs_a;

    float* out_kw = (float*)d_out;
    float* out_rt = out_kw + (size_t)NKW * 128;

    // ---- prep ----
    PrepArgs pa;
    pa.W[0] = Wr1a; pa.Wa[0] = Wr1b;
    pa.W[1] = Wl1a; pa.Wa[1] = nullptr;
    pa.W[2] = Wl1b; pa.Wa[2] = nullptr;
    pa.W[3] = Wl1c; pa.Wa[3] = nullptr;
    pa.W[4] = Wr1c; pa.Wa[4] = nullptr;
    pa.W[5] = Wr2a; pa.Wa[5] = Wr2b;
    pa.W[6] = Wl2a; pa.Wa[6] = nullptr;
    pa.W[7] = Wl2b; pa.Wa[7] = nullptr;
    pa.W[8] = Wl2c; pa.Wa[8] = nullptr;
    pa.W[9] = Wr2c; pa.Wa[9] = nullptr;
    pa.b1a = bl1a; pa.b1b = bl1b; pa.b2a = bl2a; pa.b2b = bl2b;
    prep_k<<<641, 256, 0, stream>>>(pa, Wt, bc1, bc2);
    unsigned short* W0 = Wt + 0 * 16384;
    unsigned short* W1 = Wt + 1 * 16384;
    unsigned short* W2 = Wt + 2 * 16384;
    unsigned short* W3 = Wt + 3 * 16384;
    unsigned short* W4 = Wt + 4 * 16384;
    unsigned short* W5 = Wt + 5 * 16384;
    unsigned short* W6 = Wt + 6 * 16384;
    unsigned short* W7 = Wt + 7 * 16384;
    unsigned short* W8 = Wt + 8 * 16384;
    unsigned short* W9 = Wt + 9 * 16384;

    // ---- fused bucket build ----
    hipMemsetAsync(bcnt3, 0, 3 * NBMAX * 4, stream);
    Rels R;
    int hA = 128, hB = 128, hC = 64;
    int sA = (EA + 8191) / 8192, sB = (EB + 8191) / 8192, sC = (EC + 8191) / 8192;
    R.r[0] = {src_a, dst_a, EA, nb_kw, NKW, 0, hA, 0, sA, 0,
              bcnt3, boff_a, bcur3, pairs_a, sp_a, goff_a, invd_a};
    R.r[1] = {src_b, dst_b, EB, nb_kw, NKW, hA, hB, sA, sB, nb_kw,
              bcnt3 + NBMAX, boff_b, bcur3 + NBMAX, pairs_b, sp_b, goff_b, invd_b};
    R.r[2] = {src_c, dst_c, EC, nb_rt, NRT, hA + hB, hC, sA + sB, sC, 2 * nb_kw,
              bcnt3 + 2 * NBMAX, boff_c, bcur3 + 2 * NBMAX, pairs_c, sp_c, goff_c, invd_c};
    bhist3_k<<<hA + hB + hC, 256, 0, stream>>>(R);
    bscan3_k<<<3, 1024, 0, stream>>>(R);
    bscatter3_k<<<sA + sB + sC, 256, 0, stream>>>(R);
    sortb3_k<<<2 * nb_kw + nb_rt, 256, 0, stream>>>(R);

    const int kwB = (NKW + 63) / 64, rtB = (NRT + 63) / 64;

    // ---- layer 1 ----
    GemmJobs G1;
    G1.Akw = x_kw; G1.Nkw = NKW; G1.Wk1 = W0; G1.bk = bc1; G1.Zkw = Zkw; G1.Wk2 = W2; G1.Ckw = Yb;
    G1.Art = x_rt; G1.Nrt = NRT; G1.Wr1 = W4; G1.br = bl1c; G1.Zrt = Zrt;
    G1.Wr2 = W1; G1.Crt2 = Ya; G1.Wr3 = W3; G1.Crt3 = Yc;
    G1.kwBlocks = kwB;
    gemm3_k<1><<<kwB + rtB, 256, 0, stream>>>(G1);

    AggJob JK1 = {Zkw, NKW, sp_a, goff_a, invd_a, Ya, sp_b, goff_b, invd_b, Yb, 2,
                  nullptr, kw1_bf};
    AggJob JR1 = {Zrt, NRT, sp_c, goff_c, invd_c, Yc, nullptr, nullptr, nullptr, nullptr, 1,
                  nullptr, rt1_bf};
    bagg2_k<1, 1><<<nb_kw + nb_rt, 512, 0, stream>>>(JK1, JR1, nb_kw);

    // ---- layer 2 ----
    GemmJobs G2;
    G2.Akw = kw1_bf; G2.Nkw = NKW; G2.Wk1 = W5; G2.bk = bc2; G2.Zkw = Zkw; G2.Wk2 = W7; G2.Ckw = Yb;
    G2.Art = rt1_bf; G2.Nrt = NRT; G2.Wr1 = W9; G2.br = bl2c; G2.Zrt = Zrt;
    G2.Wr2 = W6; G2.Crt2 = Ya; G2.Wr3 = W8; G2.Crt3 = Yc;
    G2.kwBlocks = kwB;
    gemm3_k<0><<<kwB + rtB, 256, 0, stream>>>(G2);

    AggJob JK2 = {Zkw, NKW, sp_a, goff_a, invd_a, Ya, sp_b, goff_b, invd_b, Yb, 2,
                  out_kw, nullptr};
    AggJob JR2 = {Zrt, NRT, sp_c, goff_c, invd_c, Yc, nullptr, nullptr, nullptr, nullptr, 1,
                  out_rt, nullptr};
    bagg2_k<0, 0><<<nb_kw + nb_rt, 512, 0, stream>>>(JK2, JR2, nb_kw);
}